// Round 5
// baseline (359.726 us; speedup 1.0000x reference)
//
#include <hip/hip_runtime.h>
#include <math.h>

#define MAXN 0.996f /* (1-PROJ_EPS)/sqrt(c) */

__device__ __forceinline__ float wredsum(float v) {
#pragma unroll
  for (int o = 32; o > 0; o >>= 1) v += __shfl_xor(v, o);
  return v;
}

__device__ __forceinline__ float artanh_f(float x) {
  x = fminf(fmaxf(x, -1.0f + 1e-7f), 1.0f - 1e-7f);
  return 0.5f * (log1pf(x) - log1pf(-x));
}

// HypAgg+HypAct+logmap0 nonlinear chain applied to one aggregated row value
__device__ __forceinline__ float chainB(float acc) {
  float n0 = sqrtf(wredsum(acc * acc));
  float u0 = fmaxf(n0, 1e-15f);
  float e1 = tanhf(u0) / u0;
  float c1 = fmaxf(e1 * n0, 1e-15f);
  float v = acc * e1;
  if (c1 > MAXN) { v *= MAXN / c1; c1 = MAXN; }
  v *= artanh_f(c1) / c1; // logmap0
  v = fmaxf(v, 0.f);      // relu in tangent space
  float n2 = sqrtf(wredsum(v * v));
  float u2 = fmaxf(n2, 1e-15f);
  float e2 = tanhf(u2) / u2;
  float c2 = fmaxf(e2 * n2, 1e-15f);
  v *= e2;
  if (c2 > MAXN) { v *= MAXN / c2; c2 = MAXN; }
  v *= artanh_f(c2) / c2; // final logmap0
  return v;
}

// hb = proj(expmap0(b)) — per-layer constant, once per wave
__device__ __forceinline__ void hbCalc(int j, const float* __restrict__ b,
                                       float& hbj, float& y2) {
  float bj = b[j];
  float nb = sqrtf(wredsum(bj * bj));
  float ub = fmaxf(nb, 1e-15f);
  float eb = tanhf(ub) / ub;
  float cb = fmaxf(eb * nb, 1e-15f);
  hbj = bj * eb * ((cb > MAXN) ? MAXN / cb : 1.0f);
  y2 = wredsum(hbj * hbj);
}

// HypLinear + hyp bias + logmap0 for ONE row; xs = wave-private LDS row,
// wT = LDS transposed weight [IND][64].
template <int IND>
__device__ __forceinline__ void doArow(int j, const float* xs, const float* wT,
                                       float hbj, float y2,
                                       float* __restrict__ uout) {
  float a2 = xs[j] * xs[j];
  if (IND == 128) { float x1v = xs[64 + j]; a2 += x1v * x1v; }
  float nx = sqrtf(wredsum(a2));
  float un = fmaxf(nx, 1e-15f);
  float s1 = tanhf(un) / un;
  float nv = s1 * nx;
  float nn = fmaxf(nv, 1e-15f);
  float s2 = (nn > MAXN) ? MAXN / nn : 1.0f;
  float alpha = s1 * s2;
  float xn = fmaxf(fminf(nn, MAXN), 1e-15f);

  float y = 0.f;
  for (int t = 0; t < IND; ++t) y = fmaf(xs[t], wT[t * 64 + j], y);
  float mxj = alpha * y;
  float mxn = fmaxf(sqrtf(wredsum(mxj * mxj)), 1e-15f);
  float hj = (tanhf(mxn / xn * artanh_f(xn)) / mxn) * mxj;

  float hn = fmaxf(sqrtf(wredsum(hj * hj)), 1e-15f);
  if (hn > MAXN) hj *= MAXN / hn;

  float x2 = wredsum(hj * hj);
  float xy = wredsum(hj * hbj);
  float num = (1.f + 2.f * xy + y2) * hj + (1.f - x2) * hbj;
  float den = fmaxf(1.f + 2.f * xy + x2 * y2, 1e-15f);
  float aj = num / den;

  float an = fmaxf(sqrtf(wredsum(aj * aj)), 1e-15f);
  float pn = an;
  if (an > MAXN) { aj *= MAXN / an; pn = MAXN; }
  uout[j] = (artanh_f(pn) / pn) * aj;
}

// stage B group: 4 rows (graph-local r0), t = chain(adj @ u) (+ dis)
template <int NP, bool WANTDIS>
__device__ __forceinline__ void doBgrp(int j, int r0,
                                       const float* __restrict__ adjg,
                                       const float* __restrict__ ug,
                                       float* __restrict__ tg,
                                       float* __restrict__ disg) {
  float acc[4], dsum[4];
#pragma unroll
  for (int r = 0; r < 4; ++r) { acc[r] = 0.f; dsum[r] = 0.f; }
  for (int c0 = 0; c0 < NP; c0 += 4) {
    float uv0 = ug[(c0 + 0) * 64 + j];
    float uv1 = ug[(c0 + 1) * 64 + j];
    float uv2 = ug[(c0 + 2) * 64 + j];
    float uv3 = ug[(c0 + 3) * 64 + j];
#pragma unroll
    for (int r = 0; r < 4; ++r) {
      const float4 a4 = *(const float4*)(adjg + (size_t)(r0 + r) * NP + c0);
      acc[r] = fmaf(a4.x, uv0, acc[r]);
      acc[r] = fmaf(a4.y, uv1, acc[r]);
      acc[r] = fmaf(a4.z, uv2, acc[r]);
      acc[r] = fmaf(a4.w, uv3, acc[r]);
      if (WANTDIS) {
        dsum[r] += a4.x; dsum[r] += a4.y; dsum[r] += a4.z; dsum[r] += a4.w;
      }
    }
  }
#pragma unroll
  for (int r = 0; r < 4; ++r) {
    float v = chainB(acc[r]);
    tg[(size_t)(r0 + r) * 64 + j] = v;
    if (WANTDIS && j == 0)
      disg[r0 + r] = (dsum[r] > 0.f) ? (1.0f / sqrtf(dsum[r])) : 0.f;
  }
}

// stage C group: score_i = sum_j | t_ij - dis_i * (adj @ (dis.*t))_ij |
template <int NP>
__device__ __forceinline__ void doCgrp(int j, int r0,
                                       const float* __restrict__ adjg,
                                       const float* __restrict__ tg,
                                       const float* __restrict__ dg,
                                       float* __restrict__ scoreg) {
  float acc[4];
#pragma unroll
  for (int r = 0; r < 4; ++r) acc[r] = 0.f;
  for (int c0 = 0; c0 < NP; c0 += 4) {
    float uv0 = dg[c0 + 0] * tg[(c0 + 0) * 64 + j];
    float uv1 = dg[c0 + 1] * tg[(c0 + 1) * 64 + j];
    float uv2 = dg[c0 + 2] * tg[(c0 + 2) * 64 + j];
    float uv3 = dg[c0 + 3] * tg[(c0 + 3) * 64 + j];
#pragma unroll
    for (int r = 0; r < 4; ++r) {
      const float4 a4 = *(const float4*)(adjg + (size_t)(r0 + r) * NP + c0);
      acc[r] = fmaf(a4.x, uv0, acc[r]);
      acc[r] = fmaf(a4.y, uv1, acc[r]);
      acc[r] = fmaf(a4.z, uv2, acc[r]);
      acc[r] = fmaf(a4.w, uv3, acc[r]);
    }
  }
#pragma unroll
  for (int r = 0; r < 4; ++r) {
    float d = fabsf(tg[(size_t)(r0 + r) * 64 + j] - dg[r0 + r] * acc[r]);
    d = wredsum(d);
    if (j == 0) scoreg[r0 + r] = d;
  }
}

// top-k rank-scatter (exact jax tie-break) + xn + attention projections,
// one wave per graph-local row i.
template <int NP>
__device__ __forceinline__ void doDEa(int j, int i,
                                      const float* __restrict__ scoreg,
                                      const float* __restrict__ tg,
                                      const float* __restrict__ att,
                                      float* __restrict__ xng,
                                      float* __restrict__ s1g,
                                      float* __restrict__ s2g,
                                      int* __restrict__ selg) {
  constexpr int K = NP / 2;
  float si = scoreg[i];
  float cnt = 0.f;
#pragma unroll
  for (int kk = 0; kk < NP / 64; ++kk) {
    int c = j + kk * 64;
    float v = scoreg[c];
    cnt += ((v > si) || (v == si && c < i)) ? 1.f : 0.f;
  }
  int rank = (int)wredsum(cnt);  // exact small-integer count
  if (rank < K) {
    float tv = tanhf(si);
    float v = tg[(size_t)i * 64 + j] * tv;
    xng[(size_t)rank * 64 + j] = v;
    float a = wredsum(v * att[j]);
    float b2 = wredsum(v * att[64 + j]);
    if (j == 0) {
      s1g[rank] = a;
      s2g[rank] = b2;
      selg[rank] = i;  // local index within old graph
    }
  }
}

// per-graph readout: max | mean over K rows (one wave)
__device__ __forceinline__ void doReadout(int j, int K,
                                          const float* __restrict__ xng,
                                          float* __restrict__ xrg) {
  float mx = -1e30f, sm = 0.f;
  for (int r = 0; r < K; ++r) {
    float v = xng[(size_t)r * 64 + j];
    mx = fmaxf(mx, v);
    sm += v;
  }
  xrg[j] = mx;
  xrg[64 + j] = sm * (1.0f / K);
}

// 8-block cluster barrier: monotonic counter, agent-scope atomics + fences.
__device__ __forceinline__ void cluster_bar(int* bar, int target, int tid) {
  __syncthreads();  // drains this block's stores (vmcnt 0) before arrival
  if (tid == 0) {
    __threadfence();  // release: L2 writeback to device scope
    __hip_atomic_fetch_add(bar, 1, __ATOMIC_RELAXED, __HIP_MEMORY_SCOPE_AGENT);
    while (__hip_atomic_load(bar, __ATOMIC_RELAXED, __HIP_MEMORY_SCOPE_AGENT) <
           target * 8)
      __builtin_amdgcn_s_sleep(4);
    __threadfence();  // acquire: invalidate stale cache lines
  }
  __syncthreads();
}

struct KP {
  const float* x; const int* ei; int nE;
  const float *W1, *b1, *W2, *b2, *W3, *b3, *att1, *att2;
  const float *lw1, *lb1, *lw2, *lb2, *lw3, *lb3;
  float *adj1, *adj2, *adj3, *srow, *ubuf, *t1, *t2, *t3, *dis, *score;
  float *xn1, *xn2, *s1b, *s2b, *x1, *x2;
  int *sel, *bar;
  float* out;
};

// 32 clusters x 8 blocks x 256 threads; cluster g owns graph g end-to-end.
__global__ void __launch_bounds__(256, 2) k_fwd(KP P) {
  const int tid = threadIdx.x;        // 256
  const int wib = tid >> 6;           // wave in block [0,4)
  const int j = tid & 63;
  const int g = blockIdx.x >> 3;      // cluster / graph [0,32)
  const int lb = blockIdx.x & 7;      // block in cluster
  const int wc = lb * 4 + wib;        // wave in cluster [0,32)
  const int tc = lb * 256 + tid;      // thread in cluster [0,2048)

  __shared__ float wT[8192];          // transposed weight of current layer
  __shared__ float xsAll[4 * 128];    // per-wave staging rows
  float* xs = xsAll + wib * 128;

  int* bar = P.bar + g * 64;
  float* adj1g = P.adj1 + (size_t)g * 65536;
  float* adj2g = P.adj2 + (size_t)g * 16384;
  float* adj3g = P.adj3 + (size_t)g * 4096;
  const float* xg = P.x + (size_t)g * 32768;
  float* srowg = P.srow + g * 256;
  float* ubufg = P.ubuf + (size_t)g * 16384;
  float* t1g = P.t1 + (size_t)g * 16384;
  float* t2g = P.t2 + (size_t)g * 8192;
  float* t3g = P.t3 + (size_t)g * 4096;
  float* disg = P.dis + g * 256;
  float* scoreg = P.score + g * 256;
  float* xn1g = P.xn1 + (size_t)g * 8192;
  float* xn2g = P.xn2 + (size_t)g * 4096;
  float* s1g = P.s1b + g * 128;
  float* s2g = P.s2b + g * 128;
  int* selg = P.sel + g * 128;
  float* x1g = P.x1 + g * 128;
  float* x2g = P.x2 + g * 128;

  // ---- P0: zero adj1 slice, rowsum -> srow, W1^T -> LDS -------------------
  {
    float4 z = make_float4(0.f, 0.f, 0.f, 0.f);
    for (int idx = tc * 4; idx < 65536; idx += 8192) *(float4*)(adj1g + idx) = z;
    for (int row = wc; row < 256; row += 32) {
      float a = xg[(size_t)row * 128 + j] + xg[(size_t)row * 128 + 64 + j];
      a = wredsum(a);
      if (j == 0) srowg[row] = a;
    }
    for (int idx = tid; idx < 8192; idx += 256)
      wT[(idx & 127) * 64 + (idx >> 7)] = P.W1[idx];
  }
  cluster_bar(bar, 1, tid);

  // ---- P1: edge scatter + A1 ---------------------------------------------
  {
    const int epg = P.nE >> 5;  // 4096 edges per graph, contiguous slice
    for (int e = g * epg + tc; e < (g + 1) * epg; e += 2048) {
      int r = P.ei[e] & 255, c = P.ei[P.nE + e] & 255;
      adj1g[r * 256 + c] = 0.5f * (srowg[r] + srowg[c]);
    }
    float hbj, y2;
    hbCalc(j, P.b1, hbj, y2);
    for (int row = wc; row < 256; row += 32) {
      xs[j] = xg[(size_t)row * 128 + j];
      xs[64 + j] = xg[(size_t)row * 128 + 64 + j];
      doArow<128>(j, xs, wT, hbj, y2, ubufg + (size_t)row * 64);
    }
  }
  cluster_bar(bar, 2, tid);

  // ---- P2: B1 (+ W2^T -> LDS) --------------------------------------------
  for (int grp = wc; grp < 64; grp += 32)
    doBgrp<256, true>(j, grp * 4, adj1g, ubufg, t1g, disg);
  for (int idx = tid; idx < 4096; idx += 256)
    wT[(idx & 63) * 64 + (idx >> 6)] = P.W2[idx];
  cluster_bar(bar, 3, tid);

  // ---- P3: C1 -------------------------------------------------------------
  for (int grp = wc; grp < 64; grp += 32)
    doCgrp<256>(j, grp * 4, adj1g, t1g, disg, scoreg);
  cluster_bar(bar, 4, tid);

  // ---- P4: DE1 rank-scatter ----------------------------------------------
  for (int row = wc; row < 256; row += 32)
    doDEa<256>(j, row, scoreg, t1g, P.att1, xn1g, s1g, s2g, selg);
  cluster_bar(bar, 5, tid);

  // ---- P5: adj2 + x1 readout + A2 ----------------------------------------
  {
    for (int idx = tc; idx < 16384; idx += 2048) {
      int ii = idx >> 7, jj = idx & 127;
      adj2g[idx] = fmaxf(s1g[ii] + s2g[jj], 0.f) +
                   adj1g[selg[ii] * 256 + selg[jj]];
    }
    if (wc == 0) doReadout(j, 128, xn1g, x1g);
    float hbj, y2;
    hbCalc(j, P.b2, hbj, y2);
    for (int row = wc; row < 128; row += 32) {
      xs[j] = xn1g[(size_t)row * 64 + j];
      doArow<64>(j, xs, wT, hbj, y2, ubufg + (size_t)row * 64);
    }
  }
  cluster_bar(bar, 6, tid);

  // ---- P6: B2 (+ W3^T -> LDS) --------------------------------------------
  if (wc < 32) doBgrp<128, true>(j, wc * 4, adj2g, ubufg, t2g, disg);
  for (int idx = tid; idx < 4096; idx += 256)
    wT[(idx & 63) * 64 + (idx >> 6)] = P.W3[idx];
  cluster_bar(bar, 7, tid);

  // ---- P7: C2 -------------------------------------------------------------
  doCgrp<128>(j, wc * 4, adj2g, t2g, disg, scoreg);
  cluster_bar(bar, 8, tid);

  // ---- P8: DE2 ------------------------------------------------------------
  for (int row = wc; row < 128; row += 32)
    doDEa<128>(j, row, scoreg, t2g, P.att2, xn2g, s1g, s2g, selg);
  cluster_bar(bar, 9, tid);

  // ---- P9: adj3 + x2 readout + A3 ----------------------------------------
  {
    for (int idx = tc; idx < 4096; idx += 2048) {
      int ii = idx >> 6, jj = idx & 63;
      adj3g[idx] = fmaxf(s1g[ii] + s2g[jj], 0.f) +
                   adj2g[selg[ii] * 128 + selg[jj]];
    }
    if (wc == 0) doReadout(j, 64, xn2g, x2g);
    float hbj, y2;
    hbCalc(j, P.b3, hbj, y2);
    for (int row = wc; row < 64; row += 32) {
      xs[j] = xn2g[(size_t)row * 64 + j];
      doArow<64>(j, xs, wT, hbj, y2, ubufg + (size_t)row * 64);
    }
  }
  cluster_bar(bar, 10, tid);

  // ---- P10: B3 ------------------------------------------------------------
  if (wc < 16) doBgrp<64, false>(j, wc * 4, adj3g, ubufg, t3g, nullptr);
  cluster_bar(bar, 11, tid);

  // ---- P11: t3 readout + MLP + log_softmax (wave 0 of cluster) ------------
  if (wc == 0) {
    float mx = -1e30f, sm = 0.f;
    for (int r = 0; r < 64; ++r) {
      float v = t3g[(size_t)r * 64 + j];
      mx = fmaxf(mx, v);
      sm += v;
    }
    float* S = xsAll;  // other waves of this block are done; wave-local use
    S[j] = fmaxf(x1g[j], 0.f) + fmaxf(x2g[j], 0.f) + fmaxf(mx, 0.f);
    S[64 + j] = fmaxf(x1g[64 + j], 0.f) + fmaxf(x2g[64 + j], 0.f) +
                fmaxf(sm * (1.0f / 64.0f), 0.f);
    float acc = P.lb1[j];
    for (int t = 0; t < 128; ++t) acc += S[t] * P.lw1[(size_t)j * 128 + t];
    S[128 + j] = fmaxf(acc, 0.f);
    if (j < 32) {
      float a = P.lb2[j];
      for (int t = 0; t < 64; ++t) a += S[128 + t] * P.lw2[(size_t)j * 64 + t];
      S[192 + j] = fmaxf(a, 0.f);
    }
    if (j < 6) {
      float a = P.lb3[j];
      for (int t = 0; t < 32; ++t) a += S[192 + t] * P.lw3[(size_t)j * 32 + t];
      S[224 + j] = a;
    }
    if (j < 6) {
      float m = S[224];
      for (int c = 1; c < 6; ++c) m = fmaxf(m, S[224 + c]);
      float se = 0.f;
      for (int c = 0; c < 6; ++c) se += expf(S[224 + c] - m);
      P.out[(size_t)g * 6 + j] = S[224 + j] - m - logf(se);
    }
  }
}

extern "C" void kernel_launch(void* const* d_in, const int* in_sizes, int n_in,
                              void* d_out, int out_size, void* d_ws,
                              size_t ws_size, hipStream_t stream) {
  KP hp;
  hp.x = (const float*)d_in[0];
  hp.ei = (const int*)d_in[1];
  hp.nE = in_sizes[1] / 2;
  hp.W1 = (const float*)d_in[2];
  hp.b1 = (const float*)d_in[3];
  hp.W2 = (const float*)d_in[4];
  hp.b2 = (const float*)d_in[5];
  hp.W3 = (const float*)d_in[6];
  hp.b3 = (const float*)d_in[7];
  hp.att1 = (const float*)d_in[8];
  hp.att2 = (const float*)d_in[9];
  hp.lw1 = (const float*)d_in[10];
  hp.lb1 = (const float*)d_in[11];
  hp.lw2 = (const float*)d_in[12];
  hp.lb2 = (const float*)d_in[13];
  hp.lw3 = (const float*)d_in[14];
  hp.lb3 = (const float*)d_in[15];
  hp.out = (float*)d_out;

  float* p = (float*)d_ws;
  hp.adj1 = p;  p += (size_t)32 * 65536;
  hp.adj2 = p;  p += (size_t)32 * 16384;
  hp.adj3 = p;  p += (size_t)32 * 4096;
  hp.ubuf = p;  p += (size_t)32 * 16384;
  hp.t1 = p;    p += (size_t)32 * 16384;
  hp.t2 = p;    p += (size_t)32 * 8192;
  hp.t3 = p;    p += (size_t)32 * 4096;
  hp.srow = p;  p += 32 * 256;
  hp.dis = p;   p += 32 * 256;
  hp.score = p; p += 32 * 256;
  hp.xn1 = p;   p += (size_t)32 * 8192;
  hp.xn2 = p;   p += (size_t)32 * 4096;
  hp.s1b = p;   p += 32 * 128;
  hp.s2b = p;   p += 32 * 128;
  hp.x1 = p;    p += 32 * 128;
  hp.x2 = p;    p += 32 * 128;
  hp.sel = (int*)p; p += 32 * 128;
  hp.bar = (int*)p; p += 32 * 64;

  hipMemsetAsync(hp.bar, 0, 32 * 64 * sizeof(int), stream);
  k_fwd<<<256, 256, 0, stream>>>(hp);
}

// Round 6
// 316.725 us; speedup vs baseline: 1.1358x; 1.1358x over previous
//
#include <hip/hip_runtime.h>
#include <math.h>

#define MAXN 0.996f /* (1-PROJ_EPS)/sqrt(c) */

__device__ __forceinline__ float wredsum(float v) {
#pragma unroll
  for (int o = 32; o > 0; o >>= 1) v += __shfl_xor(v, o);
  return v;
}

__device__ __forceinline__ float artanh_f(float x) {
  x = fminf(fmaxf(x, -1.0f + 1e-7f), 1.0f - 1e-7f);
  return 0.5f * (log1pf(x) - log1pf(-x));
}

// HypAgg+HypAct+logmap0 nonlinear chain applied to one aggregated row value
__device__ __forceinline__ float chainB(float acc) {
  float n0 = sqrtf(wredsum(acc * acc));
  float u0 = fmaxf(n0, 1e-15f);
  float e1 = tanhf(u0) / u0;
  float c1 = fmaxf(e1 * n0, 1e-15f);
  float v = acc * e1;
  if (c1 > MAXN) { v *= MAXN / c1; c1 = MAXN; }
  v *= artanh_f(c1) / c1; // logmap0
  v = fmaxf(v, 0.f);      // relu in tangent space
  float n2 = sqrtf(wredsum(v * v));
  float u2 = fmaxf(n2, 1e-15f);
  float e2 = tanhf(u2) / u2;
  float c2 = fmaxf(e2 * n2, 1e-15f);
  v *= e2;
  if (c2 > MAXN) { v *= MAXN / c2; c2 = MAXN; }
  v *= artanh_f(c2) / c2; // final logmap0
  return v;
}

// hb = proj(expmap0(b)) — per-layer constant, once per wave
__device__ __forceinline__ void hbCalc(int j, const float* __restrict__ b,
                                       float& hbj, float& y2) {
  float bj = b[j];
  float nb = sqrtf(wredsum(bj * bj));
  float ub = fmaxf(nb, 1e-15f);
  float eb = tanhf(ub) / ub;
  float cb = fmaxf(eb * nb, 1e-15f);
  hbj = bj * eb * ((cb > MAXN) ? MAXN / cb : 1.0f);
  y2 = wredsum(hbj * hbj);
}

// HypLinear + hyp bias + logmap0 for ONE row; xs = wave-private LDS row,
// wT = LDS transposed weight, stride-65 padded: wT[t*65 + j].
template <int IND>
__device__ __forceinline__ void doArow(int j, const float* xs, const float* wT,
                                       float hbj, float y2,
                                       float* __restrict__ uout) {
  float a2 = xs[j] * xs[j];
  if (IND == 128) { float x1v = xs[64 + j]; a2 += x1v * x1v; }
  float nx = sqrtf(wredsum(a2));
  float un = fmaxf(nx, 1e-15f);
  float s1 = tanhf(un) / un;
  float nv = s1 * nx;
  float nn = fmaxf(nv, 1e-15f);
  float s2 = (nn > MAXN) ? MAXN / nn : 1.0f;
  float alpha = s1 * s2;
  float xn = fmaxf(fminf(nn, MAXN), 1e-15f);

  float y = 0.f;
  for (int t = 0; t < IND; ++t) y = fmaf(xs[t], wT[t * 65 + j], y);
  float mxj = alpha * y;
  float mxn = fmaxf(sqrtf(wredsum(mxj * mxj)), 1e-15f);
  float hj = (tanhf(mxn / xn * artanh_f(xn)) / mxn) * mxj;

  float hn = fmaxf(sqrtf(wredsum(hj * hj)), 1e-15f);
  if (hn > MAXN) hj *= MAXN / hn;

  float x2 = wredsum(hj * hj);
  float xy = wredsum(hj * hbj);
  float num = (1.f + 2.f * xy + y2) * hj + (1.f - x2) * hbj;
  float den = fmaxf(1.f + 2.f * xy + x2 * y2, 1e-15f);
  float aj = num / den;

  float an = fmaxf(sqrtf(wredsum(aj * aj)), 1e-15f);
  float pn = an;
  if (an > MAXN) { aj *= MAXN / an; pn = MAXN; }
  uout[j] = (artanh_f(pn) / pn) * aj;
}

// stage B group: TR rows (graph-local r0), t = chain(adj @ u) (+ dis)
template <int NP, int TR, bool WANTDIS>
__device__ __forceinline__ void doBgrp(int j, int r0,
                                       const float* __restrict__ adjg,
                                       const float* __restrict__ ug,
                                       float* __restrict__ tg,
                                       float* __restrict__ disg) {
  float acc[TR], dsum[TR];
#pragma unroll
  for (int r = 0; r < TR; ++r) { acc[r] = 0.f; dsum[r] = 0.f; }
  for (int c0 = 0; c0 < NP; c0 += 4) {
    float uv0 = ug[(c0 + 0) * 64 + j];
    float uv1 = ug[(c0 + 1) * 64 + j];
    float uv2 = ug[(c0 + 2) * 64 + j];
    float uv3 = ug[(c0 + 3) * 64 + j];
#pragma unroll
    for (int r = 0; r < TR; ++r) {
      const float4 a4 = *(const float4*)(adjg + (size_t)(r0 + r) * NP + c0);
      acc[r] = fmaf(a4.x, uv0, acc[r]);
      acc[r] = fmaf(a4.y, uv1, acc[r]);
      acc[r] = fmaf(a4.z, uv2, acc[r]);
      acc[r] = fmaf(a4.w, uv3, acc[r]);
      if (WANTDIS) {
        dsum[r] += a4.x; dsum[r] += a4.y; dsum[r] += a4.z; dsum[r] += a4.w;
      }
    }
  }
#pragma unroll
  for (int r = 0; r < TR; ++r) {
    float v = chainB(acc[r]);
    tg[(size_t)(r0 + r) * 64 + j] = v;
    if (WANTDIS && j == 0)
      disg[r0 + r] = (dsum[r] > 0.f) ? (1.0f / sqrtf(dsum[r])) : 0.f;
  }
}

// stage C group: score_i = sum_j | t_ij - dis_i * (adj @ (dis.*t))_ij |
template <int NP, int TR>
__device__ __forceinline__ void doCgrp(int j, int r0,
                                       const float* __restrict__ adjg,
                                       const float* __restrict__ tg,
                                       const float* __restrict__ dg,
                                       float* __restrict__ scoreg) {
  float acc[TR];
#pragma unroll
  for (int r = 0; r < TR; ++r) acc[r] = 0.f;
  for (int c0 = 0; c0 < NP; c0 += 4) {
    float uv0 = dg[c0 + 0] * tg[(c0 + 0) * 64 + j];
    float uv1 = dg[c0 + 1] * tg[(c0 + 1) * 64 + j];
    float uv2 = dg[c0 + 2] * tg[(c0 + 2) * 64 + j];
    float uv3 = dg[c0 + 3] * tg[(c0 + 3) * 64 + j];
#pragma unroll
    for (int r = 0; r < TR; ++r) {
      const float4 a4 = *(const float4*)(adjg + (size_t)(r0 + r) * NP + c0);
      acc[r] = fmaf(a4.x, uv0, acc[r]);
      acc[r] = fmaf(a4.y, uv1, acc[r]);
      acc[r] = fmaf(a4.z, uv2, acc[r]);
      acc[r] = fmaf(a4.w, uv3, acc[r]);
    }
  }
#pragma unroll
  for (int r = 0; r < TR; ++r) {
    float d = fabsf(tg[(size_t)(r0 + r) * 64 + j] - dg[r0 + r] * acc[r]);
    d = wredsum(d);
    if (j == 0) scoreg[r0 + r] = d;
  }
}

// top-k rank-scatter (exact jax tie-break) + xn + attention projections,
// one wave per graph-local row i.
template <int NP>
__device__ __forceinline__ void doDEa(int j, int i,
                                      const float* __restrict__ scoreg,
                                      const float* __restrict__ tg,
                                      const float* __restrict__ att,
                                      float* __restrict__ xng,
                                      float* __restrict__ s1g,
                                      float* __restrict__ s2g,
                                      int* __restrict__ selg) {
  constexpr int K = NP / 2;
  float si = scoreg[i];
  float cnt = 0.f;
#pragma unroll
  for (int kk = 0; kk < NP / 64; ++kk) {
    int c = j + kk * 64;
    float v = scoreg[c];
    cnt += ((v > si) || (v == si && c < i)) ? 1.f : 0.f;
  }
  int rank = (int)wredsum(cnt);  // exact small-integer count
  if (rank < K) {
    float tv = tanhf(si);
    float v = tg[(size_t)i * 64 + j] * tv;
    xng[(size_t)rank * 64 + j] = v;
    float a = wredsum(v * att[j]);
    float b2 = wredsum(v * att[64 + j]);
    if (j == 0) {
      s1g[rank] = a;
      s2g[rank] = b2;
      selg[rank] = i;  // local index within old graph
    }
  }
}

// per-graph readout: max | mean over K rows (one wave)
__device__ __forceinline__ void doReadout(int j, int K,
                                          const float* __restrict__ xng,
                                          float* __restrict__ xrg) {
  float mx = -1e30f, sm = 0.f;
  for (int r = 0; r < K; ++r) {
    float v = xng[(size_t)r * 64 + j];
    mx = fmaxf(mx, v);
    sm += v;
  }
  xrg[j] = mx;
  xrg[64 + j] = sm * (1.0f / K);
}

// 8-block cluster barrier: monotonic counter, agent-scope atomics + fences.
__device__ __forceinline__ void cluster_bar(int* bar, int target, int tid) {
  __syncthreads();  // drains this block's stores before arrival
  if (tid == 0) {
    __threadfence();  // release
    __hip_atomic_fetch_add(bar, 1, __ATOMIC_RELAXED, __HIP_MEMORY_SCOPE_AGENT);
    while (__hip_atomic_load(bar, __ATOMIC_RELAXED, __HIP_MEMORY_SCOPE_AGENT) <
           target * 8)
      __builtin_amdgcn_s_sleep(4);
    __threadfence();  // acquire
  }
  __syncthreads();
}

struct KP {
  const float* x; const int* ei; int nE;
  const float *W1, *b1, *W2, *b2, *W3, *b3, *att1, *att2;
  const float *lw1, *lb1, *lw2, *lb2, *lw3, *lb3;
  float *adj1, *adj2, *adj3, *srow, *ubuf, *t1, *t2, *t3, *dis, *score;
  float *xn1, *xn2, *s1b, *s2b, *x1, *x2;
  int *sel, *bar;
  float* out;
};

// 32 clusters x 8 blocks x 1024 threads; cluster g owns graph g end-to-end.
// 256 blocks total = 1/CU (trivially co-resident), 16 waves/CU = 4/SIMD.
__global__ void __launch_bounds__(1024, 4) k_fwd(KP P) {
  const int tid = threadIdx.x;        // 1024
  const int wib = tid >> 6;           // wave in block [0,16)
  const int j = tid & 63;
  const int g = blockIdx.x >> 3;      // cluster / graph [0,32)
  const int lb = blockIdx.x & 7;      // block in cluster
  const int wc = lb * 16 + wib;       // wave in cluster [0,128)
  const int tc = lb * 1024 + tid;     // thread in cluster [0,8192)

  __shared__ float wT[128 * 65];      // padded transposed weight (33.3 KB)
  __shared__ float xsAll[16 * 128];   // per-wave staging rows (8 KB)
  float* xs = xsAll + wib * 128;

  int* bar = P.bar + g * 64;
  float* adj1g = P.adj1 + (size_t)g * 65536;
  float* adj2g = P.adj2 + (size_t)g * 16384;
  float* adj3g = P.adj3 + (size_t)g * 4096;
  const float* xg = P.x + (size_t)g * 32768;
  float* srowg = P.srow + g * 256;
  float* ubufg = P.ubuf + (size_t)g * 16384;
  float* t1g = P.t1 + (size_t)g * 16384;
  float* t2g = P.t2 + (size_t)g * 8192;
  float* t3g = P.t3 + (size_t)g * 4096;
  float* disg = P.dis + g * 256;
  float* scoreg = P.score + g * 256;
  float* xn1g = P.xn1 + (size_t)g * 8192;
  float* xn2g = P.xn2 + (size_t)g * 4096;
  float* s1g = P.s1b + g * 128;
  float* s2g = P.s2b + g * 128;
  int* selg = P.sel + g * 128;
  float* x1g = P.x1 + g * 128;
  float* x2g = P.x2 + g * 128;

  // ---- P0: zero adj1 slice, rowsum -> srow, W1^T -> LDS -------------------
  {
    float4 z = make_float4(0.f, 0.f, 0.f, 0.f);
    for (int idx = tc * 4; idx < 65536; idx += 32768)
      *(float4*)(adj1g + idx) = z;
    for (int row = wc; row < 256; row += 128) {
      float a = xg[(size_t)row * 128 + j] + xg[(size_t)row * 128 + 64 + j];
      a = wredsum(a);
      if (j == 0) srowg[row] = a;
    }
    for (int idx = tid; idx < 8192; idx += 1024)
      wT[(idx & 127) * 65 + (idx >> 7)] = P.W1[idx];
  }
  cluster_bar(bar, 1, tid);

  // ---- P1: edge scatter + A1 ---------------------------------------------
  {
    const int epg = P.nE >> 5;  // 4096 edges per graph, contiguous slice
    for (int e = g * epg + tc; e < (g + 1) * epg; e += 8192) {
      int r = P.ei[e] & 255, c = P.ei[P.nE + e] & 255;
      adj1g[r * 256 + c] = 0.5f * (srowg[r] + srowg[c]);
    }
    float hbj, y2;
    hbCalc(j, P.b1, hbj, y2);
    for (int row = wc; row < 256; row += 128) {
      xs[j] = xg[(size_t)row * 128 + j];
      xs[64 + j] = xg[(size_t)row * 128 + 64 + j];
      doArow<128>(j, xs, wT, hbj, y2, ubufg + (size_t)row * 64);
    }
  }
  cluster_bar(bar, 2, tid);

  // ---- P2: B1 (+ W2^T -> LDS) --------------------------------------------
  doBgrp<256, 2, true>(j, wc * 2, adj1g, ubufg, t1g, disg);
  for (int idx = tid; idx < 4096; idx += 1024)
    wT[(idx & 63) * 65 + (idx >> 6)] = P.W2[idx];
  cluster_bar(bar, 3, tid);

  // ---- P3: C1 -------------------------------------------------------------
  doCgrp<256, 2>(j, wc * 2, adj1g, t1g, disg, scoreg);
  cluster_bar(bar, 4, tid);

  // ---- P4: DE1 rank-scatter ----------------------------------------------
  for (int row = wc; row < 256; row += 128)
    doDEa<256>(j, row, scoreg, t1g, P.att1, xn1g, s1g, s2g, selg);
  cluster_bar(bar, 5, tid);

  // ---- P5: adj2 + x1 readout + A2 ----------------------------------------
  {
    for (int idx = tc; idx < 16384; idx += 8192) {
      int ii = idx >> 7, jj = idx & 127;
      adj2g[idx] = fmaxf(s1g[ii] + s2g[jj], 0.f) +
                   adj1g[selg[ii] * 256 + selg[jj]];
    }
    if (wc == 0) doReadout(j, 128, xn1g, x1g);
    float hbj, y2;
    hbCalc(j, P.b2, hbj, y2);
    {
      int row = wc;  // 128 rows, one per wave
      xs[j] = xn1g[(size_t)row * 64 + j];
      doArow<64>(j, xs, wT, hbj, y2, ubufg + (size_t)row * 64);
    }
  }
  cluster_bar(bar, 6, tid);

  // ---- P6: B2 (+ W3^T -> LDS) --------------------------------------------
  doBgrp<128, 1, true>(j, wc, adj2g, ubufg, t2g, disg);
  for (int idx = tid; idx < 4096; idx += 1024)
    wT[(idx & 63) * 65 + (idx >> 6)] = P.W3[idx];
  cluster_bar(bar, 7, tid);

  // ---- P7: C2 -------------------------------------------------------------
  doCgrp<128, 1>(j, wc, adj2g, t2g, disg, scoreg);
  cluster_bar(bar, 8, tid);

  // ---- P8: DE2 ------------------------------------------------------------
  doDEa<128>(j, wc, scoreg, t2g, P.att2, xn2g, s1g, s2g, selg);
  cluster_bar(bar, 9, tid);

  // ---- P9: adj3 + x2 readout + A3 ----------------------------------------
  {
    if (tc < 4096) {
      int ii = tc >> 6, jj = tc & 63;
      adj3g[tc] = fmaxf(s1g[ii] + s2g[jj], 0.f) +
                  adj2g[selg[ii] * 128 + selg[jj]];
    }
    if (wc == 0) doReadout(j, 64, xn2g, x2g);
    float hbj, y2;
    hbCalc(j, P.b3, hbj, y2);
    if (wc < 64) {
      int row = wc;
      xs[j] = xn2g[(size_t)row * 64 + j];
      doArow<64>(j, xs, wT, hbj, y2, ubufg + (size_t)row * 64);
    }
  }
  cluster_bar(bar, 10, tid);

  // ---- P10: B3 ------------------------------------------------------------
  if (wc < 64) doBgrp<64, 1, false>(j, wc, adj3g, ubufg, t3g, nullptr);
  cluster_bar(bar, 11, tid);

  // ---- P11: t3 readout + MLP + log_softmax (wave 0 of cluster) ------------
  if (wc == 0) {
    float mx = -1e30f, sm = 0.f;
    for (int r = 0; r < 64; ++r) {
      float v = t3g[(size_t)r * 64 + j];
      mx = fmaxf(mx, v);
      sm += v;
    }
    float* S = xsAll;  // other waves of this block are done
    S[j] = fmaxf(x1g[j], 0.f) + fmaxf(x2g[j], 0.f) + fmaxf(mx, 0.f);
    S[64 + j] = fmaxf(x1g[64 + j], 0.f) + fmaxf(x2g[64 + j], 0.f) +
                fmaxf(sm * (1.0f / 64.0f), 0.f);
    float acc = P.lb1[j];
    for (int t = 0; t < 128; ++t) acc += S[t] * P.lw1[(size_t)j * 128 + t];
    S[128 + j] = fmaxf(acc, 0.f);
    if (j < 32) {
      float a = P.lb2[j];
      for (int t = 0; t < 64; ++t) a += S[128 + t] * P.lw2[(size_t)j * 64 + t];
      S[192 + j] = fmaxf(a, 0.f);
    }
    if (j < 6) {
      float a = P.lb3[j];
      for (int t = 0; t < 32; ++t) a += S[192 + t] * P.lw3[(size_t)j * 32 + t];
      S[224 + j] = a;
    }
    if (j < 6) {
      float m = S[224];
      for (int c = 1; c < 6; ++c) m = fmaxf(m, S[224 + c]);
      float se = 0.f;
      for (int c = 0; c < 6; ++c) se += expf(S[224 + c] - m);
      P.out[(size_t)g * 6 + j] = S[224 + j] - m - logf(se);
    }
  }
}

extern "C" void kernel_launch(void* const* d_in, const int* in_sizes, int n_in,
                              void* d_out, int out_size, void* d_ws,
                              size_t ws_size, hipStream_t stream) {
  KP hp;
  hp.x = (const float*)d_in[0];
  hp.ei = (const int*)d_in[1];
  hp.nE = in_sizes[1] / 2;
  hp.W1 = (const float*)d_in[2];
  hp.b1 = (const float*)d_in[3];
  hp.W2 = (const float*)d_in[4];
  hp.b2 = (const float*)d_in[5];
  hp.W3 = (const float*)d_in[6];
  hp.b3 = (const float*)d_in[7];
  hp.att1 = (const float*)d_in[8];
  hp.att2 = (const float*)d_in[9];
  hp.lw1 = (const float*)d_in[10];
  hp.lb1 = (const float*)d_in[11];
  hp.lw2 = (const float*)d_in[12];
  hp.lb2 = (const float*)d_in[13];
  hp.lw3 = (const float*)d_in[14];
  hp.lb3 = (const float*)d_in[15];
  hp.out = (float*)d_out;

  float* p = (float*)d_ws;
  hp.adj1 = p;  p += (size_t)32 * 65536;
  hp.adj2 = p;  p += (size_t)32 * 16384;
  hp.adj3 = p;  p += (size_t)32 * 4096;
  hp.ubuf = p;  p += (size_t)32 * 16384;
  hp.t1 = p;    p += (size_t)32 * 16384;
  hp.t2 = p;    p += (size_t)32 * 8192;
  hp.t3 = p;    p += (size_t)32 * 4096;
  hp.srow = p;  p += 32 * 256;
  hp.dis = p;   p += 32 * 256;
  hp.score = p; p += 32 * 256;
  hp.xn1 = p;   p += (size_t)32 * 8192;
  hp.xn2 = p;   p += (size_t)32 * 4096;
  hp.s1b = p;   p += 32 * 128;
  hp.s2b = p;   p += 32 * 128;
  hp.x1 = p;    p += 32 * 128;
  hp.x2 = p;    p += 32 * 128;
  hp.sel = (int*)p; p += 32 * 128;
  hp.bar = (int*)p; p += 32 * 64;

  hipMemsetAsync(hp.bar, 0, 32 * 64 * sizeof(int), stream);
  k_fwd<<<256, 1024, 0, stream>>>(hp);
}

// Round 7
// 222.027 us; speedup vs baseline: 1.6202x; 1.4265x over previous
//
#include <hip/hip_runtime.h>
#include <math.h>

#define MAXN 0.996f /* (1-PROJ_EPS)/sqrt(c) */

__device__ __forceinline__ float wredsum(float v) {
#pragma unroll
  for (int o = 32; o > 0; o >>= 1) v += __shfl_xor(v, o);
  return v;
}

__device__ __forceinline__ float artanh_f(float x) {
  x = fminf(fmaxf(x, -1.0f + 1e-7f), 1.0f - 1e-7f);
  return 0.5f * (log1pf(x) - log1pf(-x));
}

// agent-scope coherent (write-through / L2-bypass) accessors: these make data
// visible across XCDs WITHOUT any buffer_wbl2/buffer_inv cache nukes.
__device__ __forceinline__ float cload(const float* p) {
  return __hip_atomic_load(p, __ATOMIC_RELAXED, __HIP_MEMORY_SCOPE_AGENT);
}
__device__ __forceinline__ int cloadi(const int* p) {
  return __hip_atomic_load(p, __ATOMIC_RELAXED, __HIP_MEMORY_SCOPE_AGENT);
}
__device__ __forceinline__ void cstore(float* p, float v) {
  __hip_atomic_store(p, v, __ATOMIC_RELAXED, __HIP_MEMORY_SCOPE_AGENT);
}
__device__ __forceinline__ void cstorei(int* p, int v) {
  __hip_atomic_store(p, v, __ATOMIC_RELAXED, __HIP_MEMORY_SCOPE_AGENT);
}

// bulk coherent global -> LDS stage: load-all-then-store-all so the N loads
// batch under one vmcnt window (no per-element round trips).
template <int N>
__device__ __forceinline__ void stageN(float* dst, const float* src, int tid) {
  float v[N];
#pragma unroll
  for (int k = 0; k < N; ++k) v[k] = cload(src + tid + k * 1024);
#pragma unroll
  for (int k = 0; k < N; ++k) dst[tid + k * 1024] = v[k];
}

// HypAgg+HypAct+logmap0 nonlinear chain applied to one aggregated row value
__device__ __forceinline__ float chainB(float acc) {
  float n0 = sqrtf(wredsum(acc * acc));
  float u0 = fmaxf(n0, 1e-15f);
  float e1 = tanhf(u0) / u0;
  float c1 = fmaxf(e1 * n0, 1e-15f);
  float v = acc * e1;
  if (c1 > MAXN) { v *= MAXN / c1; c1 = MAXN; }
  v *= artanh_f(c1) / c1; // logmap0
  v = fmaxf(v, 0.f);      // relu in tangent space
  float n2 = sqrtf(wredsum(v * v));
  float u2 = fmaxf(n2, 1e-15f);
  float e2 = tanhf(u2) / u2;
  float c2 = fmaxf(e2 * n2, 1e-15f);
  v *= e2;
  if (c2 > MAXN) { v *= MAXN / c2; c2 = MAXN; }
  v *= artanh_f(c2) / c2; // final logmap0
  return v;
}

// hb = proj(expmap0(b)) — per-layer constant, once per wave
__device__ __forceinline__ void hbCalc(int j, const float* __restrict__ b,
                                       float& hbj, float& y2) {
  float bj = b[j];
  float nb = sqrtf(wredsum(bj * bj));
  float ub = fmaxf(nb, 1e-15f);
  float eb = tanhf(ub) / ub;
  float cb = fmaxf(eb * nb, 1e-15f);
  hbj = bj * eb * ((cb > MAXN) ? MAXN / cb : 1.0f);
  y2 = wredsum(hbj * hbj);
}

// HypLinear + hyp bias + logmap0 for ONE row; xs = wave-private LDS row,
// wT = LDS transposed weight, stride-65 padded. Output u via coherent store.
template <int IND>
__device__ __forceinline__ void doArow(int j, const float* xs, const float* wT,
                                       float hbj, float y2,
                                       float* __restrict__ uout) {
  float a2 = xs[j] * xs[j];
  if (IND == 128) { float x1v = xs[64 + j]; a2 += x1v * x1v; }
  float nx = sqrtf(wredsum(a2));
  float un = fmaxf(nx, 1e-15f);
  float s1 = tanhf(un) / un;
  float nv = s1 * nx;
  float nn = fmaxf(nv, 1e-15f);
  float s2 = (nn > MAXN) ? MAXN / nn : 1.0f;
  float alpha = s1 * s2;
  float xn = fmaxf(fminf(nn, MAXN), 1e-15f);

  float y = 0.f;
  for (int t = 0; t < IND; ++t) y = fmaf(xs[t], wT[t * 65 + j], y);
  float mxj = alpha * y;
  float mxn = fmaxf(sqrtf(wredsum(mxj * mxj)), 1e-15f);
  float hj = (tanhf(mxn / xn * artanh_f(xn)) / mxn) * mxj;

  float hn = fmaxf(sqrtf(wredsum(hj * hj)), 1e-15f);
  if (hn > MAXN) hj *= MAXN / hn;

  float x2 = wredsum(hj * hj);
  float xy = wredsum(hj * hbj);
  float num = (1.f + 2.f * xy + y2) * hj + (1.f - x2) * hbj;
  float den = fmaxf(1.f + 2.f * xy + x2 * y2, 1e-15f);
  float aj = num / den;

  float an = fmaxf(sqrtf(wredsum(aj * aj)), 1e-15f);
  float pn = an;
  if (an > MAXN) { aj *= MAXN / an; pn = MAXN; }
  cstore(uout + j, (artanh_f(pn) / pn) * aj);
}

// stage B group from LDS: TR rows, t = chain(adjS @ uS) (+ dis).
// r0 = graph-local first row, r0l = block-local first row in adjS.
template <int NP, int TR, bool WANTDIS>
__device__ __forceinline__ void doBgrpL(int j, int r0, int r0l,
                                        const float* adjS, const float* uS,
                                        float* __restrict__ tg,
                                        float* __restrict__ disg) {
  float acc[TR], dsum[TR];
#pragma unroll
  for (int r = 0; r < TR; ++r) { acc[r] = 0.f; dsum[r] = 0.f; }
  for (int c0 = 0; c0 < NP; c0 += 4) {
    float uv0 = uS[(c0 + 0) * 64 + j];
    float uv1 = uS[(c0 + 1) * 64 + j];
    float uv2 = uS[(c0 + 2) * 64 + j];
    float uv3 = uS[(c0 + 3) * 64 + j];
#pragma unroll
    for (int r = 0; r < TR; ++r) {
      const float4 a4 = *(const float4*)(adjS + (r0l + r) * NP + c0);
      acc[r] = fmaf(a4.x, uv0, acc[r]);
      acc[r] = fmaf(a4.y, uv1, acc[r]);
      acc[r] = fmaf(a4.z, uv2, acc[r]);
      acc[r] = fmaf(a4.w, uv3, acc[r]);
      if (WANTDIS) {
        dsum[r] += a4.x; dsum[r] += a4.y; dsum[r] += a4.z; dsum[r] += a4.w;
      }
    }
  }
#pragma unroll
  for (int r = 0; r < TR; ++r) {
    float v = chainB(acc[r]);
    cstore(tg + (size_t)(r0 + r) * 64 + j, v);
    if (WANTDIS && j == 0)
      cstore(disg + r0 + r, (dsum[r] > 0.f) ? (1.0f / sqrtf(dsum[r])) : 0.f);
  }
}

// stage C group from LDS: score_i = sum_j | t_ij - dis_i*(adjS @ prodS)_ij |
// prodS[c*64+j] = dis[c]*t[c][j] (pre-staged); disS = dis in LDS.
template <int NP, int TR>
__device__ __forceinline__ void doCgrpL(int j, int r0, int r0l,
                                        const float* adjS, const float* prodS,
                                        const float* disS,
                                        const float* __restrict__ tg,
                                        float* __restrict__ scoreg) {
  float acc[TR];
#pragma unroll
  for (int r = 0; r < TR; ++r) acc[r] = 0.f;
  for (int c0 = 0; c0 < NP; c0 += 4) {
    float uv0 = prodS[(c0 + 0) * 64 + j];
    float uv1 = prodS[(c0 + 1) * 64 + j];
    float uv2 = prodS[(c0 + 2) * 64 + j];
    float uv3 = prodS[(c0 + 3) * 64 + j];
#pragma unroll
    for (int r = 0; r < TR; ++r) {
      const float4 a4 = *(const float4*)(adjS + (r0l + r) * NP + c0);
      acc[r] = fmaf(a4.x, uv0, acc[r]);
      acc[r] = fmaf(a4.y, uv1, acc[r]);
      acc[r] = fmaf(a4.z, uv2, acc[r]);
      acc[r] = fmaf(a4.w, uv3, acc[r]);
    }
  }
#pragma unroll
  for (int r = 0; r < TR; ++r) {
    float tval = cload(tg + (size_t)(r0 + r) * 64 + j);
    float d = fabsf(tval - disS[r0 + r] * acc[r]);
    d = wredsum(d);
    if (j == 0) cstore(scoreg + r0 + r, d);
  }
}

// top-k rank-scatter (exact jax tie-break) + xn + attention projections.
// scS = scores in LDS; one wave per graph-local row i.
template <int NP>
__device__ __forceinline__ void doDEa(int j, int i, const float* scS,
                                      const float* __restrict__ tg,
                                      const float* __restrict__ att,
                                      float* __restrict__ xng,
                                      float* __restrict__ s1g,
                                      float* __restrict__ s2g,
                                      int* __restrict__ selg) {
  constexpr int K = NP / 2;
  float si = scS[i];
  float cnt = 0.f;
#pragma unroll
  for (int kk = 0; kk < NP / 64; ++kk) {
    int c = j + kk * 64;
    float v = scS[c];
    cnt += ((v > si) || (v == si && c < i)) ? 1.f : 0.f;
  }
  int rank = (int)wredsum(cnt);  // exact small-integer count
  if (rank < K) {
    float tv = tanhf(si);
    float v = cload(tg + (size_t)i * 64 + j) * tv;
    cstore(xng + (size_t)rank * 64 + j, v);
    float a = wredsum(v * att[j]);
    float b2 = wredsum(v * att[64 + j]);
    if (j == 0) {
      cstore(s1g + rank, a);
      cstore(s2g + rank, b2);
      cstorei(selg + rank, i);
    }
  }
}

// per-graph readout: max | mean over K rows (one wave); K compile-time so
// the loop fully unrolls and the coherent loads batch.
template <int K>
__device__ __forceinline__ void doReadout(int j, const float* __restrict__ xng,
                                          float* __restrict__ xrg) {
  float mx = -1e30f, sm = 0.f;
#pragma unroll
  for (int r = 0; r < K; ++r) {
    float v = cload(xng + (size_t)r * 64 + j);
    mx = fmaxf(mx, v);
    sm += v;
  }
  cstore(xrg + j, mx);
  cstore(xrg + 64 + j, sm * (1.0f / K));
}

// 8-block cluster barrier. No cache-nuking fences: all cross-block data used
// sc1 (agent-coherent) accesses, so vmcnt(0) (inside __syncthreads) suffices
// for release, and coherent loads can't read stale lines after acquire.
__device__ __forceinline__ void cluster_bar(int* bar, int target, int tid) {
  __syncthreads();  // s_waitcnt vmcnt(0) lgkmcnt(0) + s_barrier
  if (tid == 0) {
    __hip_atomic_fetch_add(bar, 1, __ATOMIC_RELAXED, __HIP_MEMORY_SCOPE_AGENT);
    while (__hip_atomic_load(bar, __ATOMIC_RELAXED, __HIP_MEMORY_SCOPE_AGENT) <
           target * 8)
      __builtin_amdgcn_s_sleep(2);
  }
  __syncthreads();
}

struct KP {
  const float* x; const int* ei; int nE;
  const float *W1, *b1, *W2, *b2, *W3, *b3, *att1, *att2;
  const float *lw1, *lb1, *lw2, *lb2, *lw3, *lb3;
  float *adj1, *adj2, *adj3, *srow, *ubuf, *t1, *t2, *t3, *dis, *score;
  float *xn1, *xn2, *s1b, *s2b, *x1, *x2;
  int *sel, *bar;
  float* out;
};

// 32 clusters x 8 blocks x 1024 threads; cluster g owns graph g end-to-end.
__global__ void __launch_bounds__(1024, 4) k_fwd(KP P) {
  const int tid = threadIdx.x;        // 1024
  const int wib = tid >> 6;           // wave in block [0,16)
  const int j = tid & 63;
  const int g = blockIdx.x >> 3;      // cluster / graph [0,32)
  const int lb = blockIdx.x & 7;      // block in cluster
  const int wc = lb * 16 + wib;       // wave in cluster [0,128)
  const int tc = lb * 1024 + tid;     // thread in cluster [0,8192)

  __shared__ float wT[128 * 65];      // 33.3 KB transposed weight
  __shared__ float xsAll[16 * 128];   // 8 KB per-wave staging rows
  __shared__ float stage[16384];      // 64 KB u / dis.t stage
  __shared__ float adjS[8192];        // 32 KB this block's adj rows
  __shared__ float scS[256];
  __shared__ float s1S[128];
  __shared__ float s2S[128];
  __shared__ int selS[128];
  float* xs = xsAll + wib * 128;

  int* bar = P.bar + g * 64;
  float* adj1g = P.adj1 + (size_t)g * 65536;
  float* adj2g = P.adj2 + (size_t)g * 16384;
  float* adj3g = P.adj3 + (size_t)g * 4096;
  const float* xg = P.x + (size_t)g * 32768;
  float* srowg = P.srow + g * 256;
  float* ubufg = P.ubuf + (size_t)g * 16384;
  float* t1g = P.t1 + (size_t)g * 16384;
  float* t2g = P.t2 + (size_t)g * 8192;
  float* t3g = P.t3 + (size_t)g * 4096;
  float* disg = P.dis + g * 256;
  float* scoreg = P.score + g * 256;
  float* xn1g = P.xn1 + (size_t)g * 8192;
  float* xn2g = P.xn2 + (size_t)g * 4096;
  float* s1g = P.s1b + g * 128;
  float* s2g = P.s2b + g * 128;
  int* selg = P.sel + g * 128;
  float* x1g = P.x1 + g * 128;
  float* x2g = P.x2 + g * 128;

  // ---- P0: zero adj1 slice, rowsum -> srow, W1^T -> LDS -------------------
  {
#pragma unroll
    for (int k = 0; k < 8; ++k) cstore(adj1g + tc + k * 8192, 0.f);
    for (int row = wc; row < 256; row += 128) {
      float a = xg[(size_t)row * 128 + j] + xg[(size_t)row * 128 + 64 + j];
      a = wredsum(a);
      if (j == 0) cstore(srowg + row, a);
    }
    for (int idx = tid; idx < 8192; idx += 1024)
      wT[(idx & 127) * 65 + (idx >> 7)] = P.W1[idx];
  }
  cluster_bar(bar, 1, tid);

  // ---- P1: edge scatter + A1 ---------------------------------------------
  {
    if (tid < 256) scS[tid] = cload(srowg + tid);
    __syncthreads();
    const int epg = P.nE >> 5;  // 4096 edges per graph, contiguous slice
    for (int e = g * epg + tc; e < (g + 1) * epg; e += 8192) {
      int r = P.ei[e] & 255, c = P.ei[P.nE + e] & 255;
      cstore(adj1g + r * 256 + c, 0.5f * (scS[r] + scS[c]));
    }
    float hbj, y2;
    hbCalc(j, P.b1, hbj, y2);
    for (int row = wc; row < 256; row += 128) {
      xs[j] = xg[(size_t)row * 128 + j];
      xs[64 + j] = xg[(size_t)row * 128 + 64 + j];
      doArow<128>(j, xs, wT, hbj, y2, ubufg + (size_t)row * 64);
    }
  }
  cluster_bar(bar, 2, tid);

  // ---- P2: B1 from LDS (+ W2^T -> LDS) -----------------------------------
  {
    stageN<8>(adjS, adj1g + lb * 8192, tid);   // my 32 adj rows
    stageN<16>(stage, ubufg, tid);             // full u (256x64)
    __syncthreads();
    doBgrpL<256, 2, true>(j, wc * 2, wib * 2, adjS, stage, t1g, disg);
    for (int idx = tid; idx < 4096; idx += 1024)
      wT[(idx & 63) * 65 + (idx >> 6)] = P.W2[idx];
  }
  cluster_bar(bar, 3, tid);

  // ---- P3: C1 from LDS (adjS still valid) --------------------------------
  {
    if (tid < 256) scS[tid] = cload(disg + tid);
    __syncthreads();
    {
      float v[16];
#pragma unroll
      for (int k = 0; k < 16; ++k) {
        int idx = tid + k * 1024;
        v[k] = cload(t1g + idx) * scS[idx >> 6];
      }
#pragma unroll
      for (int k = 0; k < 16; ++k) stage[tid + k * 1024] = v[k];
    }
    __syncthreads();
    doCgrpL<256, 2>(j, wc * 2, wib * 2, adjS, stage, scS, t1g, scoreg);
  }
  cluster_bar(bar, 4, tid);

  // ---- P4: DE1 rank-scatter ----------------------------------------------
  {
    if (tid < 256) scS[tid] = cload(scoreg + tid);
    __syncthreads();
    for (int row = wc; row < 256; row += 128)
      doDEa<256>(j, row, scS, t1g, P.att1, xn1g, s1g, s2g, selg);
  }
  cluster_bar(bar, 5, tid);

  // ---- P5: adj2 + x1 readout + A2 ----------------------------------------
  {
    if (tid < 128) {
      s1S[tid] = cload(s1g + tid);
      s2S[tid] = cload(s2g + tid);
      selS[tid] = cloadi(selg + tid);
    }
    __syncthreads();
    for (int idx = tc; idx < 16384; idx += 8192) {
      int ii = idx >> 7, jj = idx & 127;
      cstore(adj2g + idx, fmaxf(s1S[ii] + s2S[jj], 0.f) +
                              cload(adj1g + selS[ii] * 256 + selS[jj]));
    }
    if (wc == 0) doReadout<128>(j, xn1g, x1g);
    float hbj, y2;
    hbCalc(j, P.b2, hbj, y2);
    {
      int row = wc;  // 128 rows, one per wave
      xs[j] = cload(xn1g + (size_t)row * 64 + j);
      doArow<64>(j, xs, wT, hbj, y2, ubufg + (size_t)row * 64);
    }
  }
  cluster_bar(bar, 6, tid);

  // ---- P6: B2 from LDS (+ W3^T -> LDS) -----------------------------------
  {
    stageN<2>(adjS, adj2g + lb * 2048, tid);   // my 16 adj rows (x128)
    stageN<8>(stage, ubufg, tid);              // u2 (128x64)
    __syncthreads();
    doBgrpL<128, 1, true>(j, wc, wib, adjS, stage, t2g, disg);
    for (int idx = tid; idx < 4096; idx += 1024)
      wT[(idx & 63) * 65 + (idx >> 6)] = P.W3[idx];
  }
  cluster_bar(bar, 7, tid);

  // ---- P7: C2 from LDS ----------------------------------------------------
  {
    if (tid < 128) scS[tid] = cload(disg + tid);
    __syncthreads();
    {
      float v[8];
#pragma unroll
      for (int k = 0; k < 8; ++k) {
        int idx = tid + k * 1024;
        v[k] = cload(t2g + idx) * scS[idx >> 6];
      }
#pragma unroll
      for (int k = 0; k < 8; ++k) stage[tid + k * 1024] = v[k];
    }
    __syncthreads();
    doCgrpL<128, 1>(j, wc, wib, adjS, stage, scS, t2g, scoreg);
  }
  cluster_bar(bar, 8, tid);

  // ---- P8: DE2 ------------------------------------------------------------
  {
    if (tid < 128) scS[tid] = cload(scoreg + tid);
    __syncthreads();
    doDEa<128>(j, wc, scS, t2g, P.att2, xn2g, s1g, s2g, selg);
  }
  cluster_bar(bar, 9, tid);

  // ---- P9: adj3 + x2 readout + A3 ----------------------------------------
  {
    if (tid < 64) {
      s1S[tid] = cload(s1g + tid);
      s2S[tid] = cload(s2g + tid);
      selS[tid] = cloadi(selg + tid);
    }
    __syncthreads();
    if (tc < 4096) {
      int ii = tc >> 6, jj = tc & 63;
      cstore(adj3g + tc, fmaxf(s1S[ii] + s2S[jj], 0.f) +
                             cload(adj2g + selS[ii] * 128 + selS[jj]));
    }
    if (wc == 0) doReadout<64>(j, xn2g, x2g);
    float hbj, y2;
    hbCalc(j, P.b3, hbj, y2);
    if (wc < 64) {
      int row = wc;
      xs[j] = cload(xn2g + (size_t)row * 64 + j);
      doArow<64>(j, xs, wT, hbj, y2, ubufg + (size_t)row * 64);
    }
  }
  cluster_bar(bar, 10, tid);

  // ---- P10: B3 from LDS (blocks 0-3 only) --------------------------------
  if (lb < 4) {
    adjS[tid] = cload(adj3g + lb * 1024 + tid);  // my 16 adj rows (x64)
    stageN<4>(stage, ubufg, tid);                // u3 (64x64)
    __syncthreads();
    doBgrpL<64, 1, false>(j, wc, wib, adjS, stage, t3g, nullptr);
  }
  cluster_bar(bar, 11, tid);

  // ---- P11: t3 readout + MLP + log_softmax (wave 0 of cluster) ------------
  if (wc == 0) {
    float mx = -1e30f, sm = 0.f;
#pragma unroll
    for (int r = 0; r < 64; ++r) {
      float v = cload(t3g + (size_t)r * 64 + j);
      mx = fmaxf(mx, v);
      sm += v;
    }
    float* S = xsAll;  // other waves of this block are done
    S[j] = fmaxf(cload(x1g + j), 0.f) + fmaxf(cload(x2g + j), 0.f) +
           fmaxf(mx, 0.f);
    S[64 + j] = fmaxf(cload(x1g + 64 + j), 0.f) +
                fmaxf(cload(x2g + 64 + j), 0.f) +
                fmaxf(sm * (1.0f / 64.0f), 0.f);
    float acc = P.lb1[j];
    for (int t = 0; t < 128; ++t) acc += S[t] * P.lw1[(size_t)j * 128 + t];
    S[128 + j] = fmaxf(acc, 0.f);
    if (j < 32) {
      float a = P.lb2[j];
      for (int t = 0; t < 64; ++t) a += S[128 + t] * P.lw2[(size_t)j * 64 + t];
      S[192 + j] = fmaxf(a, 0.f);
    }
    if (j < 6) {
      float a = P.lb3[j];
      for (int t = 0; t < 32; ++t) a += S[192 + t] * P.lw3[(size_t)j * 32 + t];
      S[224 + j] = a;
    }
    if (j < 6) {
      float m = S[224];
      for (int c = 1; c < 6; ++c) m = fmaxf(m, S[224 + c]);
      float se = 0.f;
      for (int c = 0; c < 6; ++c) se += expf(S[224 + c] - m);
      P.out[(size_t)g * 6 + j] = S[224 + j] - m - logf(se);
    }
  }
}

extern "C" void kernel_launch(void* const* d_in, const int* in_sizes, int n_in,
                              void* d_out, int out_size, void* d_ws,
                              size_t ws_size, hipStream_t stream) {
  KP hp;
  hp.x = (const float*)d_in[0];
  hp.ei = (const int*)d_in[1];
  hp.nE = in_sizes[1] / 2;
  hp.W1 = (const float*)d_in[2];
  hp.b1 = (const float*)d_in[3];
  hp.W2 = (const float*)d_in[4];
  hp.b2 = (const float*)d_in[5];
  hp.W3 = (const float*)d_in[6];
  hp.b3 = (const float*)d_in[7];
  hp.att1 = (const float*)d_in[8];
  hp.att2 = (const float*)d_in[9];
  hp.lw1 = (const float*)d_in[10];
  hp.lb1 = (const float*)d_in[11];
  hp.lw2 = (const float*)d_in[12];
  hp.lb2 = (const float*)d_in[13];
  hp.lw3 = (const float*)d_in[14];
  hp.lb3 = (const float*)d_in[15];
  hp.out = (float*)d_out;

  float* p = (float*)d_ws;
  hp.adj1 = p;  p += (size_t)32 * 65536;
  hp.adj2 = p;  p += (size_t)32 * 16384;
  hp.adj3 = p;  p += (size_t)32 * 4096;
  hp.ubuf = p;  p += (size_t)32 * 16384;
  hp.t1 = p;    p += (size_t)32 * 16384;
  hp.t2 = p;    p += (size_t)32 * 8192;
  hp.t3 = p;    p += (size_t)32 * 4096;
  hp.srow = p;  p += 32 * 256;
  hp.dis = p;   p += 32 * 256;
  hp.score = p; p += 32 * 256;
  hp.xn1 = p;   p += (size_t)32 * 8192;
  hp.xn2 = p;   p += (size_t)32 * 4096;
  hp.s1b = p;   p += 32 * 128;
  hp.s2b = p;   p += 32 * 128;
  hp.x1 = p;    p += 32 * 128;
  hp.x2 = p;    p += 32 * 128;
  hp.sel = (int*)p; p += 32 * 128;
  hp.bar = (int*)p; p += 32 * 64;

  hipMemsetAsync(hp.bar, 0, 32 * 64 * sizeof(int), stream);
  k_fwd<<<256, 1024, 0, stream>>>(hp);
}

// Round 8
// 213.029 us; speedup vs baseline: 1.6886x; 1.0422x over previous
//
#include <hip/hip_runtime.h>
#include <math.h>

#define MAXN 0.996f /* (1-PROJ_EPS)/sqrt(c) */

__device__ __forceinline__ float wredsum(float v) {
#pragma unroll
  for (int o = 32; o > 0; o >>= 1) v += __shfl_xor(v, o);
  return v;
}

__device__ __forceinline__ float artanh_f(float x) {
  x = fminf(fmaxf(x, -1.0f + 1e-7f), 1.0f - 1e-7f);
  return 0.5f * (log1pf(x) - log1pf(-x));
}

// ---- agent-scope coherent accessors (cross-XCD visible, no cache nukes) ----
__device__ __forceinline__ float cload(const float* p) {
  return __hip_atomic_load(p, __ATOMIC_RELAXED, __HIP_MEMORY_SCOPE_AGENT);
}
__device__ __forceinline__ int cloadi(const int* p) {
  return __hip_atomic_load(p, __ATOMIC_RELAXED, __HIP_MEMORY_SCOPE_AGENT);
}
__device__ __forceinline__ void cstore(float* p, float v) {
  __hip_atomic_store(p, v, __ATOMIC_RELAXED, __HIP_MEMORY_SCOPE_AGENT);
}
__device__ __forceinline__ void cstorei(int* p, int v) {
  __hip_atomic_store(p, v, __ATOMIC_RELAXED, __HIP_MEMORY_SCOPE_AGENT);
}
// 64-bit coherent store of two consecutive floats (element index must be even)
__device__ __forceinline__ void cstore64(float* p, float lo, float hi) {
  unsigned long long u =
      ((unsigned long long)__float_as_uint(hi) << 32) | __float_as_uint(lo);
  __hip_atomic_store((unsigned long long*)p, u, __ATOMIC_RELAXED,
                     __HIP_MEMORY_SCOPE_AGENT);
}
// lane j holds element j's value; even lanes store the {j, j+1} pair as u64
__device__ __forceinline__ void pairStore(float* base, int j, float v) {
  float o = __shfl_xor(v, 1);
  if ((j & 1) == 0) cstore64(base + j, v, o);
}
// bulk coherent global -> LDS stage via u64: batched loads then LDS stores
template <int N>
__device__ __forceinline__ void stage64(float* dst, const float* src, int tid) {
  const unsigned long long* s = (const unsigned long long*)src;
  unsigned long long* d = (unsigned long long*)dst;
  unsigned long long v[N];
#pragma unroll
  for (int k = 0; k < N; ++k)
    v[k] = __hip_atomic_load(s + tid + k * 1024, __ATOMIC_RELAXED,
                             __HIP_MEMORY_SCOPE_AGENT);
#pragma unroll
  for (int k = 0; k < N; ++k) d[tid + k * 1024] = v[k];
}

// HypAgg+HypAct+logmap0 nonlinear chain applied to one aggregated row value
__device__ __forceinline__ float chainB(float acc) {
  float n0 = sqrtf(wredsum(acc * acc));
  float u0 = fmaxf(n0, 1e-15f);
  float e1 = tanhf(u0) / u0;
  float c1 = fmaxf(e1 * n0, 1e-15f);
  float v = acc * e1;
  if (c1 > MAXN) { v *= MAXN / c1; c1 = MAXN; }
  v *= artanh_f(c1) / c1; // logmap0
  v = fmaxf(v, 0.f);      // relu in tangent space
  float n2 = sqrtf(wredsum(v * v));
  float u2 = fmaxf(n2, 1e-15f);
  float e2 = tanhf(u2) / u2;
  float c2 = fmaxf(e2 * n2, 1e-15f);
  v *= e2;
  if (c2 > MAXN) { v *= MAXN / c2; c2 = MAXN; }
  v *= artanh_f(c2) / c2; // final logmap0
  return v;
}

// hb = proj(expmap0(b)) — per-layer constant, once per wave
__device__ __forceinline__ void hbCalc(int j, const float* __restrict__ b,
                                       float& hbj, float& y2) {
  float bj = b[j];
  float nb = sqrtf(wredsum(bj * bj));
  float ub = fmaxf(nb, 1e-15f);
  float eb = tanhf(ub) / ub;
  float cb = fmaxf(eb * nb, 1e-15f);
  hbj = bj * eb * ((cb > MAXN) ? MAXN / cb : 1.0f);
  y2 = wredsum(hbj * hbj);
}

// HypLinear + hyp bias + logmap0 for ONE row; xs = wave-private LDS row,
// wT = LDS transposed weight, stride-65 padded. Output: paired u64 store.
template <int IND>
__device__ __forceinline__ void doArow(int j, const float* xs, const float* wT,
                                       float hbj, float y2,
                                       float* __restrict__ uout) {
  float a2 = xs[j] * xs[j];
  if (IND == 128) { float x1v = xs[64 + j]; a2 += x1v * x1v; }
  float nx = sqrtf(wredsum(a2));
  float un = fmaxf(nx, 1e-15f);
  float s1 = tanhf(un) / un;
  float nv = s1 * nx;
  float nn = fmaxf(nv, 1e-15f);
  float s2 = (nn > MAXN) ? MAXN / nn : 1.0f;
  float alpha = s1 * s2;
  float xn = fmaxf(fminf(nn, MAXN), 1e-15f);

  float y = 0.f;
  for (int t = 0; t < IND; ++t) y = fmaf(xs[t], wT[t * 65 + j], y);
  float mxj = alpha * y;
  float mxn = fmaxf(sqrtf(wredsum(mxj * mxj)), 1e-15f);
  float hj = (tanhf(mxn / xn * artanh_f(xn)) / mxn) * mxj;

  float hn = fmaxf(sqrtf(wredsum(hj * hj)), 1e-15f);
  if (hn > MAXN) hj *= MAXN / hn;

  float x2 = wredsum(hj * hj);
  float xy = wredsum(hj * hbj);
  float num = (1.f + 2.f * xy + y2) * hj + (1.f - x2) * hbj;
  float den = fmaxf(1.f + 2.f * xy + x2 * y2, 1e-15f);
  float aj = num / den;

  float an = fmaxf(sqrtf(wredsum(aj * aj)), 1e-15f);
  float pn = an;
  if (an > MAXN) { aj *= MAXN / an; pn = MAXN; }
  pairStore(uout, j, (artanh_f(pn) / pn) * aj);
}

// stage B: TR rows from LDS adj panel + LDS u; t via paired u64 stores.
// r0 = graph-local first row, r0l = block-local first row in adjS.
template <int NP, int TR, bool WANTDIS>
__device__ __forceinline__ void doBgrpL(int j, int r0, int r0l,
                                        const float* adjS, const float* uS,
                                        float* __restrict__ tg,
                                        float* __restrict__ disg) {
  float acc[TR], dsum[TR];
#pragma unroll
  for (int r = 0; r < TR; ++r) { acc[r] = 0.f; dsum[r] = 0.f; }
  for (int c0 = 0; c0 < NP; c0 += 4) {
    float uv0 = uS[(c0 + 0) * 64 + j];
    float uv1 = uS[(c0 + 1) * 64 + j];
    float uv2 = uS[(c0 + 2) * 64 + j];
    float uv3 = uS[(c0 + 3) * 64 + j];
#pragma unroll
    for (int r = 0; r < TR; ++r) {
      const float4 a4 = *(const float4*)(adjS + (r0l + r) * NP + c0);
      acc[r] = fmaf(a4.x, uv0, acc[r]);
      acc[r] = fmaf(a4.y, uv1, acc[r]);
      acc[r] = fmaf(a4.z, uv2, acc[r]);
      acc[r] = fmaf(a4.w, uv3, acc[r]);
      if (WANTDIS) {
        dsum[r] += a4.x; dsum[r] += a4.y; dsum[r] += a4.z; dsum[r] += a4.w;
      }
    }
  }
#pragma unroll
  for (int r = 0; r < TR; ++r) {
    float v = chainB(acc[r]);
    pairStore(tg + (size_t)(r0 + r) * 64, j, v);
    if (WANTDIS && j == 0)
      cstore(disg + r0 + r, (dsum[r] > 0.f) ? (1.0f / sqrtf(dsum[r])) : 0.f);
  }
}

// stage C: score_i = sum_j | t_ij - dis_i*(adjS @ (dis.*t))_ij |.
// tS = raw t in LDS; dis applied at use (same values as precomputed product).
template <int NP, int TR>
__device__ __forceinline__ void doCgrpL(int j, int r0, int r0l,
                                        const float* adjS, const float* tS,
                                        const float* disS,
                                        float* __restrict__ scoreg) {
  float acc[TR];
#pragma unroll
  for (int r = 0; r < TR; ++r) acc[r] = 0.f;
  for (int c0 = 0; c0 < NP; c0 += 4) {
    float uv0 = disS[c0 + 0] * tS[(c0 + 0) * 64 + j];
    float uv1 = disS[c0 + 1] * tS[(c0 + 1) * 64 + j];
    float uv2 = disS[c0 + 2] * tS[(c0 + 2) * 64 + j];
    float uv3 = disS[c0 + 3] * tS[(c0 + 3) * 64 + j];
#pragma unroll
    for (int r = 0; r < TR; ++r) {
      const float4 a4 = *(const float4*)(adjS + (r0l + r) * NP + c0);
      acc[r] = fmaf(a4.x, uv0, acc[r]);
      acc[r] = fmaf(a4.y, uv1, acc[r]);
      acc[r] = fmaf(a4.z, uv2, acc[r]);
      acc[r] = fmaf(a4.w, uv3, acc[r]);
    }
  }
#pragma unroll
  for (int r = 0; r < TR; ++r) {
    float d = fabsf(tS[(r0 + r) * 64 + j] - disS[r0 + r] * acc[r]);
    d = wredsum(d);
    if (j == 0) cstore(scoreg + r0 + r, d);
  }
}

// top-k rank-scatter (exact jax tie-break) + xn + attention projections.
// scS = scores in LDS; tS = t in LDS; one wave per graph-local row i.
template <int NP>
__device__ __forceinline__ void doDEa(int j, int i, const float* scS,
                                      const float* tS,
                                      const float* __restrict__ att,
                                      float* __restrict__ xng,
                                      float* __restrict__ s1g,
                                      float* __restrict__ s2g,
                                      int* __restrict__ selg) {
  constexpr int K = NP / 2;
  float si = scS[i];
  float cnt = 0.f;
#pragma unroll
  for (int kk = 0; kk < NP / 64; ++kk) {
    int c = j + kk * 64;
    float v = scS[c];
    cnt += ((v > si) || (v == si && c < i)) ? 1.f : 0.f;
  }
  int rank = (int)wredsum(cnt);  // exact small-integer count (wave-uniform)
  if (rank < K) {
    float tv = tanhf(si);
    float v = tS[i * 64 + j] * tv;
    pairStore(xng + (size_t)rank * 64, j, v);
    float a = wredsum(v * att[j]);
    float b2 = wredsum(v * att[64 + j]);
    if (j == 0) {
      cstore(s1g + rank, a);
      cstore(s2g + rank, b2);
      cstorei(selg + rank, i);
    }
  }
}

// per-graph readout: max | mean over K rows (one wave)
template <int K>
__device__ __forceinline__ void doReadout(int j, const float* __restrict__ xng,
                                          float* __restrict__ xrg) {
  float mx = -1e30f, sm = 0.f;
#pragma unroll
  for (int r = 0; r < K; ++r) {
    float v = cload(xng + (size_t)r * 64 + j);
    mx = fmaxf(mx, v);
    sm += v;
  }
  cstore(xrg + j, mx);
  cstore(xrg + 64 + j, sm * (1.0f / K));
}

// 8-block cluster barrier: monotonic counter, all cross-block data uses sc1
// coherent accesses so no cache writeback/invalidate is needed here.
__device__ __forceinline__ void cluster_bar(int* bar, int target, int tid) {
  __syncthreads();  // drains this block's stores (vmcnt 0) before arrival
  if (tid == 0) {
    __hip_atomic_fetch_add(bar, 1, __ATOMIC_RELAXED, __HIP_MEMORY_SCOPE_AGENT);
    while (__hip_atomic_load(bar, __ATOMIC_RELAXED, __HIP_MEMORY_SCOPE_AGENT) <
           target * 8)
      __builtin_amdgcn_s_sleep(2);
  }
  __syncthreads();
}

struct KP {
  const float* x; const int* ei; int nE;
  const float *W1, *b1, *W2, *b2, *W3, *b3, *att1, *att2;
  const float *lw1, *lb1, *lw2, *lb2, *lw3, *lb3;
  float *adj2, *adj3, *ubuf, *t1, *t2, *t3, *dis, *score;
  float *xn1, *xn2, *s1b, *s2b, *x1, *x2;
  int *sel, *bar;
  float* out;
};

// 32 clusters x 8 blocks x 1024 threads; cluster g owns graph g end-to-end.
// adj1 lives ONLY in LDS (each block builds its 32-row panel from the edge
// list); adj2/adj3 rows are produced by the block owning the source row.
__global__ void __launch_bounds__(1024, 4) k_fwd(KP P) {
  const int tid = threadIdx.x;        // 1024
  const int wib = tid >> 6;           // wave in block [0,16)
  const int j = tid & 63;
  const int g = blockIdx.x >> 3;      // cluster / graph [0,32)
  const int lb = blockIdx.x & 7;      // block in cluster
  const int wc = lb * 16 + wib;       // wave in cluster [0,128)

  __shared__ float wT[128 * 65];      // 33.3 KB transposed weight (padded)
  __shared__ float xsAll[16 * 128];   // 8 KB per-wave staging rows
  __shared__ float stage[16384];      // 64 KB u / t broadcast stage
  __shared__ float adjS[8192];        // 32 KB this block's adj row panel
  __shared__ float scS[256];          // srow / dis / score (phase-reused)
  __shared__ float s1S[128];
  __shared__ float s2S[128];
  __shared__ int selS[128];
  float* xs = xsAll + wib * 128;

  int* bar = P.bar + g * 64;
  float* adj2g = P.adj2 + (size_t)g * 16384;
  float* adj3g = P.adj3 + (size_t)g * 4096;
  const float* xg = P.x + (size_t)g * 32768;
  float* ubufg = P.ubuf + (size_t)g * 16384;
  float* t1g = P.t1 + (size_t)g * 16384;
  float* t2g = P.t2 + (size_t)g * 8192;
  float* t3g = P.t3 + (size_t)g * 4096;
  float* disg = P.dis + g * 256;
  float* scoreg = P.score + g * 256;
  float* xn1g = P.xn1 + (size_t)g * 8192;
  float* xn2g = P.xn2 + (size_t)g * 4096;
  float* s1g = P.s1b + g * 128;
  float* s2g = P.s2b + g * 128;
  int* selg = P.sel + g * 128;
  float* x1g = P.x1 + g * 128;
  float* x2g = P.x2 + g * 128;

  // ---- P0: W1^T + srow (block-local) + adj1 panel from edges + A1 --------
  {
    for (int idx = tid; idx < 8192; idx += 1024)
      wT[(idx & 127) * 65 + (idx >> 7)] = P.W1[idx];
    for (int row = wib * 16; row < wib * 16 + 16; ++row) {
      float a = xg[(size_t)row * 128 + j] + xg[(size_t)row * 128 + 64 + j];
      a = wredsum(a);
      if (j == 0) scS[row] = a;  // srow
    }
    for (int k = tid; k < 8192; k += 1024) adjS[k] = 0.f;
    __syncthreads();
    const int epg = P.nE >> 5;  // 4096 edges per graph, contiguous slice
    for (int e = g * epg + tid; e < (g + 1) * epg; e += 1024) {
      int r = P.ei[e] & 255;
      if ((r >> 5) == lb) {  // my 32-row panel
        int c = P.ei[P.nE + e] & 255;
        adjS[(r & 31) * 256 + c] = 0.5f * (scS[r] + scS[c]);
      }
    }
    float hbj, y2;
    hbCalc(j, P.b1, hbj, y2);
    for (int row = wc; row < 256; row += 128) {
      xs[j] = xg[(size_t)row * 128 + j];
      xs[64 + j] = xg[(size_t)row * 128 + 64 + j];
      doArow<128>(j, xs, wT, hbj, y2, ubufg + (size_t)row * 64);
    }
  }
  cluster_bar(bar, 1, tid);

  // ---- P1: B1 (u broadcast -> LDS) + W2^T ---------------------------------
  {
    stage64<8>(stage, ubufg, tid);  // full u1 (256x64)
    __syncthreads();
    doBgrpL<256, 2, true>(j, wc * 2, wib * 2, adjS, stage, t1g, disg);
    for (int idx = tid; idx < 4096; idx += 1024)
      wT[(idx & 63) * 65 + (idx >> 6)] = P.W2[idx];
  }
  cluster_bar(bar, 2, tid);

  // ---- P2: C1 (t1 broadcast -> LDS; adjS persists) -----------------------
  {
    if (tid < 256) scS[tid] = cload(disg + tid);
    stage64<8>(stage, t1g, tid);  // full t1
    __syncthreads();
    doCgrpL<256, 2>(j, wc * 2, wib * 2, adjS, stage, scS, scoreg);
  }
  cluster_bar(bar, 3, tid);

  // ---- P3: DE1 rank-scatter (t1 still in stage) --------------------------
  {
    if (tid < 256) scS[tid] = cload(scoreg + tid);
    __syncthreads();
    for (int row = wc; row < 256; row += 128)
      doDEa<256>(j, row, scS, stage, P.att1, xn1g, s1g, s2g, selg);
  }
  cluster_bar(bar, 4, tid);

  // ---- P4: adj2 rows (owner-built from LDS) + x1 readout + A2 ------------
  {
    if (tid < 128) {
      s1S[tid] = cload(s1g + tid);
      s2S[tid] = cload(s2g + tid);
      selS[tid] = cloadi(selg + tid);
    }
    __syncthreads();
    for (int idx2 = tid; idx2 < 8192; idx2 += 1024) {
      int ii = idx2 >> 6, jp = idx2 & 63;
      int sii = selS[ii];
      if ((sii >> 5) == lb) {  // I own adj1 row sii
        int jj0 = jp * 2;
        const float* arow = adjS + (sii & 31) * 256;
        float v0 = fmaxf(s1S[ii] + s2S[jj0], 0.f) + arow[selS[jj0]];
        float v1 = fmaxf(s1S[ii] + s2S[jj0 + 1], 0.f) + arow[selS[jj0 + 1]];
        cstore64(adj2g + ii * 128 + jj0, v0, v1);
      }
    }
    if (wc == 0) doReadout<128>(j, xn1g, x1g);
    float hbj, y2;
    hbCalc(j, P.b2, hbj, y2);
    {
      int row = wc;  // 128 rows, one per wave
      xs[j] = cload(xn1g + (size_t)row * 64 + j);
      doArow<64>(j, xs, wT, hbj, y2, ubufg + (size_t)row * 64);
    }
  }
  cluster_bar(bar, 5, tid);

  // ---- P5: B2 (adj2 panel + u2 -> LDS) + W3^T ----------------------------
  {
    stage64<1>(adjS, adj2g + lb * 2048, tid);  // my 16 rows (x128)
    stage64<4>(stage, ubufg, tid);             // u2 (128x64)
    __syncthreads();
    doBgrpL<128, 1, true>(j, wc, wib, adjS, stage, t2g, disg);
    for (int idx = tid; idx < 4096; idx += 1024)
      wT[(idx & 63) * 65 + (idx >> 6)] = P.W3[idx];
  }
  cluster_bar(bar, 6, tid);

  // ---- P6: C2 -------------------------------------------------------------
  {
    if (tid < 128) scS[tid] = cload(disg + tid);
    stage64<4>(stage, t2g, tid);  // full t2
    __syncthreads();
    doCgrpL<128, 1>(j, wc, wib, adjS, stage, scS, scoreg);
  }
  cluster_bar(bar, 7, tid);

  // ---- P7: DE2 (t2 still in stage) ---------------------------------------
  {
    if (tid < 128) scS[tid] = cload(scoreg + tid);
    __syncthreads();
    doDEa<128>(j, wc, scS, stage, P.att2, xn2g, s1g, s2g, selg);
  }
  cluster_bar(bar, 8, tid);

  // ---- P8: adj3 rows (owner-built from LDS) + x2 readout + A3 ------------
  {
    if (tid < 64) {
      s1S[tid] = cload(s1g + tid);
      s2S[tid] = cload(s2g + tid);
      selS[tid] = cloadi(selg + tid);
    }
    __syncthreads();
    for (int idx2 = tid; idx2 < 2048; idx2 += 1024) {
      int ii = idx2 >> 5, jp = idx2 & 31;
      int sii = selS[ii];
      if ((sii >> 4) == lb) {  // I own adj2 row sii
        int jj0 = jp * 2;
        const float* arow = adjS + (sii & 15) * 128;
        float v0 = fmaxf(s1S[ii] + s2S[jj0], 0.f) + arow[selS[jj0]];
        float v1 = fmaxf(s1S[ii] + s2S[jj0 + 1], 0.f) + arow[selS[jj0 + 1]];
        cstore64(adj3g + ii * 64 + jj0, v0, v1);
      }
    }
    if (wc == 0) doReadout<64>(j, xn2g, x2g);
    float hbj, y2;
    hbCalc(j, P.b3, hbj, y2);
    if (wc < 64) {
      int row = wc;
      xs[j] = cload(xn2g + (size_t)row * 64 + j);
      doArow<64>(j, xs, wT, hbj, y2, ubufg + (size_t)row * 64);
    }
  }
  cluster_bar(bar, 9, tid);

  // ---- P9: B3 (blocks 0-3: adj3 panel + u3 -> LDS) -----------------------
  if (lb < 4) {
    if (tid < 512) {
      unsigned long long v = __hip_atomic_load(
          (const unsigned long long*)(adj3g + lb * 1024) + tid,
          __ATOMIC_RELAXED, __HIP_MEMORY_SCOPE_AGENT);
      ((unsigned long long*)adjS)[tid] = v;
    }
    stage64<2>(stage, ubufg, tid);  // u3 (64x64)
    __syncthreads();
    doBgrpL<64, 1, false>(j, wc, wib, adjS, stage, t3g, nullptr);
  }
  cluster_bar(bar, 10, tid);

  // ---- P10: t3 readout + MLP + log_softmax (wave 0 of cluster) -----------
  if (wc == 0) {
    float mx = -1e30f, sm = 0.f;
#pragma unroll
    for (int r = 0; r < 64; ++r) {
      float v = cload(t3g + (size_t)r * 64 + j);
      mx = fmaxf(mx, v);
      sm += v;
    }
    float* S = xsAll;  // other waves of this block are done
    S[j] = fmaxf(cload(x1g + j), 0.f) + fmaxf(cload(x2g + j), 0.f) +
           fmaxf(mx, 0.f);
    S[64 + j] = fmaxf(cload(x1g + 64 + j), 0.f) +
                fmaxf(cload(x2g + 64 + j), 0.f) +
                fmaxf(sm * (1.0f / 64.0f), 0.f);
    float acc = P.lb1[j];
    for (int t = 0; t < 128; ++t) acc += S[t] * P.lw1[(size_t)j * 128 + t];
    S[128 + j] = fmaxf(acc, 0.f);
    if (j < 32) {
      float a = P.lb2[j];
      for (int t = 0; t < 64; ++t) a += S[128 + t] * P.lw2[(size_t)j * 64 + t];
      S[192 + j] = fmaxf(a, 0.f);
    }
    if (j < 6) {
      float a = P.lb3[j];
      for (int t = 0; t < 32; ++t) a += S[192 + t] * P.lw3[(size_t)j * 32 + t];
      S[224 + j] = a;
    }
    if (j < 6) {
      float m = S[224];
      for (int c = 1; c < 6; ++c) m = fmaxf(m, S[224 + c]);
      float se = 0.f;
      for (int c = 0; c < 6; ++c) se += expf(S[224 + c] - m);
      P.out[(size_t)g * 6 + j] = S[224 + j] - m - logf(se);
    }
  }
}

extern "C" void kernel_launch(void* const* d_in, const int* in_sizes, int n_in,
                              void* d_out, int out_size, void* d_ws,
                              size_t ws_size, hipStream_t stream) {
  KP hp;
  hp.x = (const float*)d_in[0];
  hp.ei = (const int*)d_in[1];
  hp.nE = in_sizes[1] / 2;
  hp.W1 = (const float*)d_in[2];
  hp.b1 = (const float*)d_in[3];
  hp.W2 = (const float*)d_in[4];
  hp.b2 = (const float*)d_in[5];
  hp.W3 = (const float*)d_in[6];
  hp.b3 = (const float*)d_in[7];
  hp.att1 = (const float*)d_in[8];
  hp.att2 = (const float*)d_in[9];
  hp.lw1 = (const float*)d_in[10];
  hp.lb1 = (const float*)d_in[11];
  hp.lw2 = (const float*)d_in[12];
  hp.lb2 = (const float*)d_in[13];
  hp.lw3 = (const float*)d_in[14];
  hp.lb3 = (const float*)d_in[15];
  hp.out = (float*)d_out;

  float* p = (float*)d_ws;
  hp.adj2 = p;  p += (size_t)32 * 16384;
  hp.adj3 = p;  p += (size_t)32 * 4096;
  hp.ubuf = p;  p += (size_t)32 * 16384;
  hp.t1 = p;    p += (size_t)32 * 16384;
  hp.t2 = p;    p += (size_t)32 * 8192;
  hp.t3 = p;    p += (size_t)32 * 4096;
  hp.dis = p;   p += 32 * 256;
  hp.score = p; p += 32 * 256;
  hp.xn1 = p;   p += (size_t)32 * 8192;
  hp.xn2 = p;   p += (size_t)32 * 4096;
  hp.s1b = p;   p += 32 * 128;
  hp.s2b = p;   p += 32 * 128;
  hp.x1 = p;    p += 32 * 128;
  hp.x2 = p;    p += 32 * 128;
  hp.sel = (int*)p; p += 32 * 128;
  hp.bar = (int*)p; p += 32 * 64;

  hipMemsetAsync(hp.bar, 0, 32 * 64 * sizeof(int), stream);
  k_fwd<<<256, 1024, 0, stream>>>(hp);
}

// Round 9
// 207.161 us; speedup vs baseline: 1.7365x; 1.0283x over previous
//
#include <hip/hip_runtime.h>
#include <math.h>

#define MAXN 0.996f /* (1-PROJ_EPS)/sqrt(c) */

typedef float f32x4 __attribute__((ext_vector_type(4)));

__device__ __forceinline__ float wredsum(float v) {
#pragma unroll
  for (int o = 32; o > 0; o >>= 1) v += __shfl_xor(v, o);
  return v;
}

__device__ __forceinline__ float artanh_f(float x) {
  x = fminf(fmaxf(x, -1.0f + 1e-7f), 1.0f - 1e-7f);
  return 0.5f * (log1pf(x) - log1pf(-x));
}

// ---- agent-scope coherent accessors (cross-XCD visible, no cache nukes) ----
__device__ __forceinline__ float cload(const float* p) {
  return __hip_atomic_load(p, __ATOMIC_RELAXED, __HIP_MEMORY_SCOPE_AGENT);
}
__device__ __forceinline__ int cloadi(const int* p) {
  return __hip_atomic_load(p, __ATOMIC_RELAXED, __HIP_MEMORY_SCOPE_AGENT);
}
__device__ __forceinline__ void cstore(float* p, float v) {
  __hip_atomic_store(p, v, __ATOMIC_RELAXED, __HIP_MEMORY_SCOPE_AGENT);
}
__device__ __forceinline__ void cstorei(int* p, int v) {
  __hip_atomic_store(p, v, __ATOMIC_RELAXED, __HIP_MEMORY_SCOPE_AGENT);
}
// 128-bit coherent store (16B-aligned): widest agent-coherent write per lane.
__device__ __forceinline__ void cstore128(float* p, float a, float b, float c,
                                          float d) {
  f32x4 v;
  v.x = a; v.y = b; v.z = c; v.w = d;
  asm volatile("global_store_dwordx4 %0, %1, off sc0 sc1" ::"v"(p), "v"(v)
               : "memory");
}
// lane j holds element j; lanes j%4==0 store the 4-element group as dwordx4
__device__ __forceinline__ void quadStore(float* base, int j, float v) {
  float v1 = __shfl_xor(v, 1);
  float v2 = __shfl_xor(v, 2);
  float v3 = __shfl_xor(v, 3);
  if ((j & 3) == 0) cstore128(base + j, v, v1, v2, v3);
}
// bulk coherent global -> LDS stage via u64: batched loads then LDS stores
template <int N>
__device__ __forceinline__ void stage64(float* dst, const float* src, int tid) {
  const unsigned long long* s = (const unsigned long long*)src;
  unsigned long long* d = (unsigned long long*)dst;
  unsigned long long v[N];
#pragma unroll
  for (int k = 0; k < N; ++k)
    v[k] = __hip_atomic_load(s + tid + k * 1024, __ATOMIC_RELAXED,
                             __HIP_MEMORY_SCOPE_AGENT);
#pragma unroll
  for (int k = 0; k < N; ++k) d[tid + k * 1024] = v[k];
}

// HypAgg+HypAct+logmap0 nonlinear chain applied to one aggregated row value
__device__ __forceinline__ float chainB(float acc) {
  float n0 = sqrtf(wredsum(acc * acc));
  float u0 = fmaxf(n0, 1e-15f);
  float e1 = tanhf(u0) / u0;
  float c1 = fmaxf(e1 * n0, 1e-15f);
  float v = acc * e1;
  if (c1 > MAXN) { v *= MAXN / c1; c1 = MAXN; }
  v *= artanh_f(c1) / c1; // logmap0
  v = fmaxf(v, 0.f);      // relu in tangent space
  float n2 = sqrtf(wredsum(v * v));
  float u2 = fmaxf(n2, 1e-15f);
  float e2 = tanhf(u2) / u2;
  float c2 = fmaxf(e2 * n2, 1e-15f);
  v *= e2;
  if (c2 > MAXN) { v *= MAXN / c2; c2 = MAXN; }
  v *= artanh_f(c2) / c2; // final logmap0
  return v;
}

// hb = proj(expmap0(b)) — per-layer constant, once per wave
__device__ __forceinline__ void hbCalc(int j, const float* __restrict__ b,
                                       float& hbj, float& y2) {
  float bj = b[j];
  float nb = sqrtf(wredsum(bj * bj));
  float ub = fmaxf(nb, 1e-15f);
  float eb = tanhf(ub) / ub;
  float cb = fmaxf(eb * nb, 1e-15f);
  hbj = bj * eb * ((cb > MAXN) ? MAXN / cb : 1.0f);
  y2 = wredsum(hbj * hbj);
}

// HypLinear + hyp bias + logmap0 for ONE row; xs = wave-private LDS row,
// wT = LDS transposed weight, stride-65 padded. Output: dwordx4 sc1 store.
template <int IND>
__device__ __forceinline__ void doArow(int j, const float* xs, const float* wT,
                                       float hbj, float y2,
                                       float* __restrict__ uout) {
  float a2 = xs[j] * xs[j];
  if (IND == 128) { float x1v = xs[64 + j]; a2 += x1v * x1v; }
  float nx = sqrtf(wredsum(a2));
  float un = fmaxf(nx, 1e-15f);
  float s1 = tanhf(un) / un;
  float nv = s1 * nx;
  float nn = fmaxf(nv, 1e-15f);
  float s2 = (nn > MAXN) ? MAXN / nn : 1.0f;
  float alpha = s1 * s2;
  float xn = fmaxf(fminf(nn, MAXN), 1e-15f);

  float y = 0.f;
  for (int t = 0; t < IND; ++t) y = fmaf(xs[t], wT[t * 65 + j], y);
  float mxj = alpha * y;
  float mxn = fmaxf(sqrtf(wredsum(mxj * mxj)), 1e-15f);
  float hj = (tanhf(mxn / xn * artanh_f(xn)) / mxn) * mxj;

  float hn = fmaxf(sqrtf(wredsum(hj * hj)), 1e-15f);
  if (hn > MAXN) hj *= MAXN / hn;

  float x2 = wredsum(hj * hj);
  float xy = wredsum(hj * hbj);
  float num = (1.f + 2.f * xy + y2) * hj + (1.f - x2) * hbj;
  float den = fmaxf(1.f + 2.f * xy + x2 * y2, 1e-15f);
  float aj = num / den;

  float an = fmaxf(sqrtf(wredsum(aj * aj)), 1e-15f);
  float pn = an;
  if (an > MAXN) { aj *= MAXN / an; pn = MAXN; }
  quadStore(uout, j, (artanh_f(pn) / pn) * aj);
}

// stage B: TR rows from LDS adj panel + LDS u; t via dwordx4 sc1 stores.
template <int NP, int TR, bool WANTDIS>
__device__ __forceinline__ void doBgrpL(int j, int r0, int r0l,
                                        const float* adjS, const float* uS,
                                        float* __restrict__ tg,
                                        float* __restrict__ disg) {
  float acc[TR], dsum[TR];
#pragma unroll
  for (int r = 0; r < TR; ++r) { acc[r] = 0.f; dsum[r] = 0.f; }
  for (int c0 = 0; c0 < NP; c0 += 4) {
    float uv0 = uS[(c0 + 0) * 64 + j];
    float uv1 = uS[(c0 + 1) * 64 + j];
    float uv2 = uS[(c0 + 2) * 64 + j];
    float uv3 = uS[(c0 + 3) * 64 + j];
#pragma unroll
    for (int r = 0; r < TR; ++r) {
      const float4 a4 = *(const float4*)(adjS + (r0l + r) * NP + c0);
      acc[r] = fmaf(a4.x, uv0, acc[r]);
      acc[r] = fmaf(a4.y, uv1, acc[r]);
      acc[r] = fmaf(a4.z, uv2, acc[r]);
      acc[r] = fmaf(a4.w, uv3, acc[r]);
      if (WANTDIS) {
        dsum[r] += a4.x; dsum[r] += a4.y; dsum[r] += a4.z; dsum[r] += a4.w;
      }
    }
  }
#pragma unroll
  for (int r = 0; r < TR; ++r) {
    float v = chainB(acc[r]);
    quadStore(tg + (size_t)(r0 + r) * 64, j, v);
    if (WANTDIS && j == 0)
      cstore(disg + r0 + r, (dsum[r] > 0.f) ? (1.0f / sqrtf(dsum[r])) : 0.f);
  }
}

// stage C: score_i = sum_j | t_ij - dis_i*(adjS @ (dis.*t))_ij |
template <int NP, int TR>
__device__ __forceinline__ void doCgrpL(int j, int r0, int r0l,
                                        const float* adjS, const float* tS,
                                        const float* disS,
                                        float* __restrict__ scoreg) {
  float acc[TR];
#pragma unroll
  for (int r = 0; r < TR; ++r) acc[r] = 0.f;
  for (int c0 = 0; c0 < NP; c0 += 4) {
    float uv0 = disS[c0 + 0] * tS[(c0 + 0) * 64 + j];
    float uv1 = disS[c0 + 1] * tS[(c0 + 1) * 64 + j];
    float uv2 = disS[c0 + 2] * tS[(c0 + 2) * 64 + j];
    float uv3 = disS[c0 + 3] * tS[(c0 + 3) * 64 + j];
#pragma unroll
    for (int r = 0; r < TR; ++r) {
      const float4 a4 = *(const float4*)(adjS + (r0l + r) * NP + c0);
      acc[r] = fmaf(a4.x, uv0, acc[r]);
      acc[r] = fmaf(a4.y, uv1, acc[r]);
      acc[r] = fmaf(a4.z, uv2, acc[r]);
      acc[r] = fmaf(a4.w, uv3, acc[r]);
    }
  }
#pragma unroll
  for (int r = 0; r < TR; ++r) {
    float d = fabsf(tS[(r0 + r) * 64 + j] - disS[r0 + r] * acc[r]);
    d = wredsum(d);
    if (j == 0) cstore(scoreg + r0 + r, d);
  }
}

// top-k rank-scatter (exact jax tie-break) + xn + attention projections.
template <int NP>
__device__ __forceinline__ void doDEa(int j, int i, const float* scS,
                                      const float* tS,
                                      const float* __restrict__ att,
                                      float* __restrict__ xng,
                                      float* __restrict__ s1g,
                                      float* __restrict__ s2g,
                                      int* __restrict__ selg) {
  constexpr int K = NP / 2;
  float si = scS[i];
  float cnt = 0.f;
#pragma unroll
  for (int kk = 0; kk < NP / 64; ++kk) {
    int c = j + kk * 64;
    float v = scS[c];
    cnt += ((v > si) || (v == si && c < i)) ? 1.f : 0.f;
  }
  int rank = (int)wredsum(cnt);  // exact small-integer count (wave-uniform)
  if (rank < K) {
    float tv = tanhf(si);
    float v = tS[i * 64 + j] * tv;
    quadStore(xng + (size_t)rank * 64, j, v);
    float a = wredsum(v * att[j]);
    float b2 = wredsum(v * att[64 + j]);
    if (j == 0) {
      cstore(s1g + rank, a);
      cstore(s2g + rank, b2);
      cstorei(selg + rank, i);
    }
  }
}

// per-graph readout into block-local LDS (producer==consumer block)
template <int K>
__device__ __forceinline__ void doReadoutL(int j, const float* __restrict__ xng,
                                           float* xrl) {
  float mx = -1e30f, sm = 0.f;
#pragma unroll
  for (int r = 0; r < K; ++r) {
    float v = cload(xng + (size_t)r * 64 + j);
    mx = fmaxf(mx, v);
    sm += v;
  }
  xrl[j] = mx;
  xrl[64 + j] = sm * (1.0f / K);
}

// 8-block cluster barrier: monotonic counter; all cross-block data uses sc1
// coherent accesses so no cache writeback/invalidate is needed here.
__device__ __forceinline__ void cluster_bar(int* bar, int target, int tid) {
  __syncthreads();  // drains this block's stores (vmcnt 0) before arrival
  if (tid == 0) {
    __hip_atomic_fetch_add(bar, 1, __ATOMIC_RELAXED, __HIP_MEMORY_SCOPE_AGENT);
    while (__hip_atomic_load(bar, __ATOMIC_RELAXED, __HIP_MEMORY_SCOPE_AGENT) <
           target * 8)
      __builtin_amdgcn_s_sleep(2);
  }
  __syncthreads();
}

struct KP {
  const float* x; const int* ei; int nE;
  const float *W1, *b1, *W2, *b2, *W3, *b3, *att1, *att2;
  const float *lw1, *lb1, *lw2, *lb2, *lw3, *lb3;
  float *adj2, *adj3, *ubuf, *t1, *t2, *t3, *srow, *dis, *score;
  float *xn1, *xn2, *s1b, *s2b;
  int *sel, *bar;
  float* out;
};

// 32 clusters x 8 blocks x 1024 threads; cluster g owns graph g end-to-end.
// adj1 lives ONLY in LDS; block lb owns graph rows [lb*32, lb*32+32).
__global__ void __launch_bounds__(1024, 4) k_fwd(KP P) {
  const int tid = threadIdx.x;        // 1024
  const int wib = tid >> 6;           // wave in block [0,16)
  const int j = tid & 63;
  const int g = blockIdx.x >> 3;      // cluster / graph [0,32)
  const int lb = blockIdx.x & 7;      // block in cluster
  const int wc = lb * 16 + wib;       // wave in cluster [0,128)

  __shared__ float wT[128 * 65];      // 33.3 KB transposed weight (padded)
  __shared__ float xsAll[16 * 128];   // 8 KB per-wave staging rows
  __shared__ float stage[16384];      // 64 KB u / t broadcast stage
  __shared__ float adjS[8192];        // 32 KB this block's adj row panel
  __shared__ float scS[256];          // srow / dis / score (phase-reused)
  __shared__ float s1S[128];
  __shared__ float s2S[128];
  __shared__ int selS[128];
  __shared__ float x12S[256];         // x1 | x2 readouts (block 0 only)
  float* xs = xsAll + wib * 128;

  int* bar = P.bar + g * 64;
  float* adj2g = P.adj2 + (size_t)g * 16384;
  float* adj3g = P.adj3 + (size_t)g * 4096;
  const float* xg = P.x + (size_t)g * 32768;
  float* srowg = P.srow + g * 256;
  float* ubufg = P.ubuf + (size_t)g * 16384;
  float* t1g = P.t1 + (size_t)g * 16384;
  float* t2g = P.t2 + (size_t)g * 8192;
  float* t3g = P.t3 + (size_t)g * 4096;
  float* disg = P.dis + g * 256;
  float* scoreg = P.score + g * 256;
  float* xn1g = P.xn1 + (size_t)g * 8192;
  float* xn2g = P.xn2 + (size_t)g * 4096;
  float* s1g = P.s1b + g * 128;
  float* s2g = P.s2b + g * 128;
  int* selg = P.sel + g * 128;

  // ---- P0: W1^T; fused A1+srow on OWN 32 rows (x read once); zero adjS ---
  {
    for (int idx = tid; idx < 8192; idx += 1024)
      wT[(idx & 127) * 65 + (idx >> 7)] = P.W1[idx];
    for (int k = tid; k < 8192; k += 1024) adjS[k] = 0.f;
    float hbj, y2;
    hbCalc(j, P.b1, hbj, y2);
    for (int rr = 0; rr < 2; ++rr) {
      const int row = lb * 32 + wib * 2 + rr;
      xs[j] = xg[(size_t)row * 128 + j];
      xs[64 + j] = xg[(size_t)row * 128 + 64 + j];
      float a = xs[j] + xs[64 + j];
      a = wredsum(a);
      if (j == 0) cstore(srowg + row, a);
      doArow<128>(j, xs, wT, hbj, y2, ubufg + (size_t)row * 64);
    }
  }
  cluster_bar(bar, 1, tid);

  // ---- P1: srow -> LDS; edge panel build; u1 broadcast; B1 ---------------
  {
    if (tid < 256) scS[tid] = cload(srowg + tid);
    stage64<8>(stage, ubufg, tid);  // full u1 (256x64)
    __syncthreads();
    const int epg = P.nE >> 5;  // 4096 edges per graph, contiguous slice
    for (int e = g * epg + tid; e < (g + 1) * epg; e += 1024) {
      int r = P.ei[e] & 255;
      if ((r >> 5) == lb) {  // my 32-row panel
        int c = P.ei[P.nE + e] & 255;
        adjS[(r & 31) * 256 + c] = 0.5f * (scS[r] + scS[c]);
      }
    }
    __syncthreads();
    doBgrpL<256, 2, true>(j, lb * 32 + wib * 2, wib * 2, adjS, stage, t1g,
                          disg);
    for (int idx = tid; idx < 4096; idx += 1024)
      wT[(idx & 63) * 65 + (idx >> 6)] = P.W2[idx];
  }
  cluster_bar(bar, 2, tid);

  // ---- P2: C1 (t1 broadcast -> LDS; adjS persists) -----------------------
  {
    if (tid < 256) scS[tid] = cload(disg + tid);
    stage64<8>(stage, t1g, tid);  // full t1
    __syncthreads();
    doCgrpL<256, 2>(j, lb * 32 + wib * 2, wib * 2, adjS, stage, scS, scoreg);
  }
  cluster_bar(bar, 3, tid);

  // ---- P3: DE1 rank-scatter (t1 still in stage) --------------------------
  {
    if (tid < 256) scS[tid] = cload(scoreg + tid);
    __syncthreads();
    for (int row = wc; row < 256; row += 128)
      doDEa<256>(j, row, scS, stage, P.att1, xn1g, s1g, s2g, selg);
  }
  cluster_bar(bar, 4, tid);

  // ---- P4: adj2 rows (owner-built, dwordx4) + x1 readout + A2 ------------
  {
    if (tid < 128) {
      s1S[tid] = cload(s1g + tid);
      s2S[tid] = cload(s2g + tid);
      selS[tid] = cloadi(selg + tid);
    }
    __syncthreads();
    for (int q = tid; q < 4096; q += 1024) {  // 128 rows x 32 quads
      int ii = q >> 5, jj0 = (q & 31) * 4;
      int sii = selS[ii];
      if ((sii >> 5) == lb) {  // I own adj1 row sii
        const float* arow = adjS + (sii & 31) * 256;
        float s1v = s1S[ii];
        float v0 = fmaxf(s1v + s2S[jj0 + 0], 0.f) + arow[selS[jj0 + 0]];
        float v1 = fmaxf(s1v + s2S[jj0 + 1], 0.f) + arow[selS[jj0 + 1]];
        float v2 = fmaxf(s1v + s2S[jj0 + 2], 0.f) + arow[selS[jj0 + 2]];
        float v3 = fmaxf(s1v + s2S[jj0 + 3], 0.f) + arow[selS[jj0 + 3]];
        cstore128(adj2g + ii * 128 + jj0, v0, v1, v2, v3);
      }
    }
    if (wc == 0) doReadoutL<128>(j, xn1g, x12S);
    float hbj, y2;
    hbCalc(j, P.b2, hbj, y2);
    {
      int row = wc;  // 128 rows, one per wave
      xs[j] = cload(xn1g + (size_t)row * 64 + j);
      doArow<64>(j, xs, wT, hbj, y2, ubufg + (size_t)row * 64);
    }
  }
  cluster_bar(bar, 5, tid);

  // ---- P5: B2 (adj2 panel + u2 -> LDS) + W3^T ----------------------------
  {
    stage64<1>(adjS, adj2g + lb * 2048, tid);  // my 16 rows (x128)
    stage64<4>(stage, ubufg, tid);             // u2 (128x64)
    __syncthreads();
    doBgrpL<128, 1, true>(j, wc, wib, adjS, stage, t2g, disg);
    for (int idx = tid; idx < 4096; idx += 1024)
      wT[(idx & 63) * 65 + (idx >> 6)] = P.W3[idx];
  }
  cluster_bar(bar, 6, tid);

  // ---- P6: C2 -------------------------------------------------------------
  {
    if (tid < 128) scS[tid] = cload(disg + tid);
    stage64<4>(stage, t2g, tid);  // full t2
    __syncthreads();
    doCgrpL<128, 1>(j, wc, wib, adjS, stage, scS, scoreg);
  }
  cluster_bar(bar, 7, tid);

  // ---- P7: DE2 (t2 still in stage) ---------------------------------------
  {
    if (tid < 128) scS[tid] = cload(scoreg + tid);
    __syncthreads();
    doDEa<128>(j, wc, scS, stage, P.att2, xn2g, s1g, s2g, selg);
  }
  cluster_bar(bar, 8, tid);

  // ---- P8: adj3 rows (owner-built, dwordx4) + x2 readout + A3 ------------
  {
    if (tid < 64) {
      s1S[tid] = cload(s1g + tid);
      s2S[tid] = cload(s2g + tid);
      selS[tid] = cloadi(selg + tid);
    }
    __syncthreads();
    {  // 64 rows x 16 quads = 1024 entries
      int ii = tid >> 4, jj0 = (tid & 15) * 4;
      int sii = selS[ii];
      if ((sii >> 4) == lb) {  // I own adj2 row sii
        const float* arow = adjS + (sii & 15) * 128;
        float s1v = s1S[ii];
        float v0 = fmaxf(s1v + s2S[jj0 + 0], 0.f) + arow[selS[jj0 + 0]];
        float v1 = fmaxf(s1v + s2S[jj0 + 1], 0.f) + arow[selS[jj0 + 1]];
        float v2 = fmaxf(s1v + s2S[jj0 + 2], 0.f) + arow[selS[jj0 + 2]];
        float v3 = fmaxf(s1v + s2S[jj0 + 3], 0.f) + arow[selS[jj0 + 3]];
        cstore128(adj3g + ii * 64 + jj0, v0, v1, v2, v3);
      }
    }
    if (wc == 0) doReadoutL<64>(j, xn2g, x12S + 128);
    float hbj, y2;
    hbCalc(j, P.b3, hbj, y2);
    if (wc < 64) {
      int row = wc;
      xs[j] = cload(xn2g + (size_t)row * 64 + j);
      doArow<64>(j, xs, wT, hbj, y2, ubufg + (size_t)row * 64);
    }
  }
  cluster_bar(bar, 9, tid);

  // ---- P9: B3 (blocks 0-3: adj3 panel + u3 -> LDS) -----------------------
  if (lb < 4) {
    if (tid < 512) {
      unsigned long long v = __hip_atomic_load(
          (const unsigned long long*)(adj3g + lb * 1024) + tid,
          __ATOMIC_RELAXED, __HIP_MEMORY_SCOPE_AGENT);
      ((unsigned long long*)adjS)[tid] = v;
    }
    stage64<2>(stage, ubufg, tid);  // u3 (64x64)
    __syncthreads();
    doBgrpL<64, 1, false>(j, wc, wib, adjS, stage, t3g, nullptr);
  }
  cluster_bar(bar, 10, tid);

  // ---- P10: t3 readout + MLP + log_softmax (wave 0 of cluster) -----------
  if (wc == 0) {
    float mx = -1e30f, sm = 0.f;
#pragma unroll
    for (int r = 0; r < 64; ++r) {
      float v = cload(t3g + (size_t)r * 64 + j);
      mx = fmaxf(mx, v);
      sm += v;
    }
    float* S = xsAll;  // other waves of this block are done
    S[j] = fmaxf(x12S[j], 0.f) + fmaxf(x12S[128 + j], 0.f) + fmaxf(mx, 0.f);
    S[64 + j] = fmaxf(x12S[64 + j], 0.f) + fmaxf(x12S[192 + j], 0.f) +
                fmaxf(sm * (1.0f / 64.0f), 0.f);
    float acc = P.lb1[j];
    for (int t = 0; t < 128; ++t) acc += S[t] * P.lw1[(size_t)j * 128 + t];
    S[128 + j] = fmaxf(acc, 0.f);
    if (j < 32) {
      float a = P.lb2[j];
      for (int t = 0; t < 64; ++t) a += S[128 + t] * P.lw2[(size_t)j * 64 + t];
      S[192 + j] = fmaxf(a, 0.f);
    }
    if (j < 6) {
      float a = P.lb3[j];
      for (int t = 0; t < 32; ++t) a += S[192 + t] * P.lw3[(size_t)j * 32 + t];
      S[224 + j] = a;
    }
    if (j < 6) {
      float m = S[224];
      for (int c = 1; c < 6; ++c) m = fmaxf(m, S[224 + c]);
      float se = 0.f;
      for (int c = 0; c < 6; ++c) se += expf(S[224 + c] - m);
      P.out[(size_t)g * 6 + j] = S[224 + j] - m - logf(se);
    }
  }
}

extern "C" void kernel_launch(void* const* d_in, const int* in_sizes, int n_in,
                              void* d_out, int out_size, void* d_ws,
                              size_t ws_size, hipStream_t stream) {
  KP hp;
  hp.x = (const float*)d_in[0];
  hp.ei = (const int*)d_in[1];
  hp.nE = in_sizes[1] / 2;
  hp.W1 = (const float*)d_in[2];
  hp.b1 = (const float*)d_in[3];
  hp.W2 = (const float*)d_in[4];
  hp.b2 = (const float*)d_in[5];
  hp.W3 = (const float*)d_in[6];
  hp.b3 = (const float*)d_in[7];
  hp.att1 = (const float*)d_in[8];
  hp.att2 = (const float*)d_in[9];
  hp.lw1 = (const float*)d_in[10];
  hp.lb1 = (const float*)d_in[11];
  hp.lw2 = (const float*)d_in[12];
  hp.lb2 = (const float*)d_in[13];
  hp.lw3 = (const float*)d_in[14];
  hp.lb3 = (const float*)d_in[15];
  hp.out = (float*)d_out;

  float* p = (float*)d_ws;
  hp.adj2 = p;  p += (size_t)32 * 16384;
  hp.adj3 = p;  p += (size_t)32 * 4096;
  hp.ubuf = p;  p += (size_t)32 * 16384;
  hp.t1 = p;    p += (size_t)32 * 16384;
  hp.t2 = p;    p += (size_t)32 * 8192;
  hp.t3 = p;    p += (size_t)32 * 4096;
  hp.srow = p;  p += 32 * 256;
  hp.dis = p;   p += 32 * 256;
  hp.score = p; p += 32 * 256;
  hp.xn1 = p;   p += (size_t)32 * 8192;
  hp.xn2 = p;   p += (size_t)32 * 4096;
  hp.s1b = p;   p += 32 * 128;
  hp.s2b = p;   p += 32 * 128;
  hp.sel = (int*)p; p += 32 * 128;
  hp.bar = (int*)p; p += 32 * 64;

  hipMemsetAsync(hp.bar, 0, 32 * 64 * sizeof(int), stream);
  k_fwd<<<256, 1024, 0, stream>>>(hp);
}